// Round 5
// baseline (670.066 us; speedup 1.0000x reference)
//
#include <hip/hip_runtime.h>
#include <hip/hip_bf16.h>

#define DIM 128
#define NLAYER 4

typedef _Float16 f16x8 __attribute__((ext_vector_type(8)));
typedef _Float16 f16x2 __attribute__((ext_vector_type(2)));
typedef float f32x4 __attribute__((ext_vector_type(4)));

// ---------------- CSR build ----------------

__global__ void k_count(const int* __restrict__ dst, int E, int* __restrict__ counts) {
    int e = blockIdx.x * blockDim.x + threadIdx.x;
    if (e < E) atomicAdd(&counts[dst[e]], 1);
}

__global__ __launch_bounds__(1024) void k_scan1(const int* __restrict__ in, int n,
                                                int* __restrict__ partial,
                                                int* __restrict__ blockSums) {
    __shared__ int sd[1024];
    int tid = threadIdx.x;
    int i = blockIdx.x * 1024 + tid;
    int v = (i < n) ? in[i] : 0;
    sd[tid] = v;
    __syncthreads();
    for (int off = 1; off < 1024; off <<= 1) {
        int t = (tid >= off) ? sd[tid - off] : 0;
        __syncthreads();
        sd[tid] += t;
        __syncthreads();
    }
    if (i < n) partial[i] = sd[tid];
    if (tid == 1023) blockSums[blockIdx.x] = sd[1023];
}

__global__ void k_scan2(int* __restrict__ bs, int nb) {
    int lane = threadIdx.x;
    int v = (lane < nb) ? bs[lane] : 0;
    for (int off = 1; off < 64; off <<= 1) {
        int t = __shfl_up(v, off, 64);
        if (lane >= off) v += t;
    }
    int ex = __shfl_up(v, 1, 64);
    if (lane == 0) ex = 0;
    if (lane < nb) bs[lane] = ex;
}

__global__ __launch_bounds__(1024) void k_scan3(const int* __restrict__ partial,
                                                const int* __restrict__ bs, int n,
                                                int* __restrict__ row_ptr,
                                                int* __restrict__ cursor) {
    int i = blockIdx.x * blockDim.x + threadIdx.x;
    if (i < n) {
        int v = partial[i] + bs[i >> 10];
        row_ptr[i + 1] = v;
        cursor[i + 1] = v;
    }
    if (i == 0) { row_ptr[0] = 0; cursor[0] = 0; }
}

__global__ void k_scatter(const int* __restrict__ srcA, const int* __restrict__ dstA,
                          const int* __restrict__ typA, const int* __restrict__ hopA,
                          int E, int* __restrict__ cursor, unsigned* __restrict__ csr) {
    int e = blockIdx.x * blockDim.x + threadIdx.x;
    if (e < E) {
        int d = dstA[e];
        int p = atomicAdd(&cursor[d], 1);
        csr[p] = (unsigned)srcA[e] | ((unsigned)typA[e] << 16) | ((unsigned)hopA[e] << 18);
    }
}

__global__ void k_bias(const float* __restrict__ b_edge, const float* __restrict__ b_hop,
                       float* __restrict__ bias_sums) {
    int t = blockIdx.x, d = threadIdx.x;
    float s = b_edge[d] + b_edge[DIM + d] + b_edge[2 * DIM + d];
    int base = t * (t + 1) / 2;
    for (int k = 1; k <= t + 1; ++k) s += b_hop[(base + k - 1) * DIM + d];
    bias_sums[t * DIM + d] = s;
}

// ---------------- f16 conversions ----------------

__global__ void k_convX(const float* __restrict__ in, _Float16* __restrict__ out, int n) {
    int i = (blockIdx.x * blockDim.x + threadIdx.x) * 8;
    if (i >= n) return;
    float4 a = ((const float4*)(in + i))[0];
    float4 b = ((const float4*)(in + i))[1];
    f16x8 o;
    o[0] = (_Float16)a.x; o[1] = (_Float16)a.y; o[2] = (_Float16)a.z; o[3] = (_Float16)a.w;
    o[4] = (_Float16)b.x; o[5] = (_Float16)b.y; o[6] = (_Float16)b.z; o[7] = (_Float16)b.w;
    *(f16x8*)(out + i) = o;
}

// 13 weight matrices, fp32 row-major [k][n] -> f16 transposed [n][k]
__global__ __launch_bounds__(256) void k_convW(const float* __restrict__ W_edge,
                                               const float* __restrict__ W_hop,
                                               _Float16* __restrict__ Wt) {
    int s = blockIdx.x;
    const float* src = (s < 3) ? (W_edge + (size_t)s * DIM * DIM)
                               : (W_hop + (size_t)(s - 3) * DIM * DIM);
    _Float16* dstp = Wt + (size_t)s * DIM * DIM;
    for (int it = 0; it < 64; ++it) {
        int e = it * 256 + threadIdx.x;
        int n = e >> 7, k = e & 127;
        dstp[e] = (_Float16)src[k * DIM + n];
    }
}

// -------- phase 1: CSR gather-aggregate, 4-edge unrolled for MLP --------
// A slot map: 0..2 = edge types, 3+(k-1) = hop k

struct GatherArgs {
    const _Float16* xt;    // xh[t]   (types + hop1)
    const _Float16* xm1;   // xh[t-1] (hop2)
    const _Float16* xm2;   // xh[t-2] (hop3)
    const _Float16* xm3;   // xh[t-3] (hop4)
    _Float16* A;           // [7][N][128]
    const int* row_ptr;
    const unsigned* csr;
    int t, N;
};

__global__ __launch_bounds__(256) void k_gather(GatherArgs a) {
    const int wid = threadIdx.x >> 6, lane = threadIdx.x & 63;
    const int node = blockIdx.x * 4 + wid;   // one node per wave
    if (node >= a.N) return;
    const size_t NS = (size_t)a.N * DIM;
    const int hopMax = a.t + 1;

    float t0x = 0, t0y = 0, t1x = 0, t1y = 0, t2x = 0, t2y = 0;
    float h1x = 0, h1y = 0, h2x = 0, h2y = 0, h3x = 0, h3y = 0, h4x = 0, h4y = 0;

    const int e0 = a.row_ptr[node], e1 = a.row_ptr[node + 1];
    int e = e0;
    const int e4 = e0 + ((e1 - e0) & ~3);

    // 4-edge unroll: batch 8 row-loads in flight, then wave-uniform accumulate.
    for (; e < e4; e += 4) {
        unsigned mm[4];
        #pragma unroll
        for (int j = 0; j < 4; ++j) mm[j] = a.csr[e + j];
        f16x2 vv[4], ww[4];
        #pragma unroll
        for (int j = 0; j < 4; ++j) {
            const int src = mm[j] & 0xFFFF;
            const int hop = (int)(mm[j] >> 18);
            vv[j] = ((const f16x2*)(a.xt + (size_t)src * DIM))[lane];
            // inactive/hop<=1 aliases the type row -> L1 hit, no extra L2 traffic
            const _Float16* ph =
                (hop == 2 && hopMax >= 2) ? a.xm1 :
                (hop == 3 && hopMax >= 3) ? a.xm2 :
                (hop == 4 && hopMax >= 4) ? a.xm3 : a.xt;
            ww[j] = ((const f16x2*)(ph + (size_t)src * DIM))[lane];
        }
        #pragma unroll
        for (int j = 0; j < 4; ++j) {
            const int typ = (mm[j] >> 16) & 3;
            const int hop = (int)(mm[j] >> 18);
            const float vx = (float)vv[j][0], vy = (float)vv[j][1];
            if (typ == 0)      { t0x += vx; t0y += vy; }   // wave-uniform branches
            else if (typ == 1) { t1x += vx; t1y += vy; }
            else               { t2x += vx; t2y += vy; }
            if (hop >= 1 && hop <= hopMax) {
                const float wx = (float)ww[j][0], wy = (float)ww[j][1];
                if (hop == 1)      { h1x += wx; h1y += wy; }
                else if (hop == 2) { h2x += wx; h2y += wy; }
                else if (hop == 3) { h3x += wx; h3y += wy; }
                else               { h4x += wx; h4y += wy; }
            }
        }
    }
    for (; e < e1; ++e) {
        const unsigned m = a.csr[e];
        const int src = m & 0xFFFF;
        const int typ = (m >> 16) & 3;
        const int hop = (int)(m >> 18);
        const f16x2 v = ((const f16x2*)(a.xt + (size_t)src * DIM))[lane];
        const float vx = (float)v[0], vy = (float)v[1];
        if (typ == 0)      { t0x += vx; t0y += vy; }
        else if (typ == 1) { t1x += vx; t1y += vy; }
        else               { t2x += vx; t2y += vy; }
        if (hop >= 1 && hop <= hopMax) {
            const _Float16* ph = (hop == 2) ? a.xm1 : (hop == 3) ? a.xm2 :
                                 (hop == 4) ? a.xm3 : a.xt;
            const f16x2 w = ((const f16x2*)(ph + (size_t)src * DIM))[lane];
            const float wx = (float)w[0], wy = (float)w[1];
            if (hop == 1)      { h1x += wx; h1y += wy; }
            else if (hop == 2) { h2x += wx; h2y += wy; }
            else if (hop == 3) { h3x += wx; h3y += wy; }
            else               { h4x += wx; h4y += wy; }
        }
    }

    _Float16* base = a.A + (size_t)node * DIM;
    f16x2 o;
    o[0] = (_Float16)t0x; o[1] = (_Float16)t0y; ((f16x2*)(base + 0 * NS))[lane] = o;
    o[0] = (_Float16)t1x; o[1] = (_Float16)t1y; ((f16x2*)(base + 1 * NS))[lane] = o;
    o[0] = (_Float16)t2x; o[1] = (_Float16)t2y; ((f16x2*)(base + 2 * NS))[lane] = o;
    o[0] = (_Float16)h1x; o[1] = (_Float16)h1y; ((f16x2*)(base + 3 * NS))[lane] = o;
    if (a.t >= 1) { o[0] = (_Float16)h2x; o[1] = (_Float16)h2y; ((f16x2*)(base + 4 * NS))[lane] = o; }
    if (a.t >= 2) { o[0] = (_Float16)h3x; o[1] = (_Float16)h3y; ((f16x2*)(base + 5 * NS))[lane] = o; }
    if (a.t >= 3) { o[0] = (_Float16)h4x; o[1] = (_Float16)h4y; ((f16x2*)(base + 6 * NS))[lane] = o; }
}

// -------- phase 2: C = sum_s A_s @ W_s, fused bias+relu+residual+L2norm --------
// wave = 16 rows x 128 cols (acc 32 VGPR), block = 64 rows -> 782 blocks (~3/CU)

struct GemmArgs {
    const _Float16* A;     // [7][N][128]
    const _Float16* Wt;    // 13 x [n][k] f16
    const _Float16* xin;   // xh[t], residual source
    const float* bias;     // bias_sums + t*128
    float* outf;           // fp32 out (final layer) or null
    _Float16* outh;        // xh[t+1] or null
    int nsub, N;
    int wsel[7];
};

__global__ __launch_bounds__(256) void k_gemm(GemmArgs a) {
    const int wv = threadIdx.x >> 6, lane = threadIdx.x & 63;
    const int rowBase = blockIdx.x * 64 + wv * 16;
    const int lr = lane & 15, lg = lane >> 4;
    const size_t NS = (size_t)a.N * DIM;

    f32x4 acc[8];
    #pragma unroll
    for (int ct = 0; ct < 8; ++ct) acc[ct] = (f32x4){0.f, 0.f, 0.f, 0.f};

    int r = rowBase + lr;
    if (r >= a.N) r = a.N - 1;

    for (int s = 0; s < a.nsub; ++s) {
        const _Float16* As = a.A + (size_t)s * NS + (size_t)r * DIM;
        const _Float16* Bs = a.Wt + (size_t)a.wsel[s] * (DIM * DIM);
        #pragma unroll
        for (int ks = 0; ks < 4; ++ks) {
            const int kb = ks * 32 + lg * 8;
            const f16x8 af = *(const f16x8*)(As + kb);
            #pragma unroll
            for (int ct = 0; ct < 8; ++ct) {
                const f16x8 bf = *(const f16x8*)(Bs + (size_t)(ct * 16 + lr) * DIM + kb);
                acc[ct] = __builtin_amdgcn_mfma_f32_16x16x32_f16(af, bf, acc[ct], 0, 0, 0);
            }
        }
    }

    float bv[8];
    #pragma unroll
    for (int ct = 0; ct < 8; ++ct) bv[ct] = a.bias[ct * 16 + lr];

    // C/D layout: col = lane&15, row = (lane>>4)*4 + reg
    #pragma unroll
    for (int rg = 0; rg < 4; ++rg) {
        const int row = rowBase + lg * 4 + rg;
        const int rr = (row < a.N) ? row : a.N - 1;
        float v[8];
        float ss = 0.f;
        #pragma unroll
        for (int ct = 0; ct < 8; ++ct) {
            const float xval = (float)a.xin[(size_t)rr * DIM + ct * 16 + lr];
            const float tv = fmaxf(acc[ct][rg] + bv[ct], 0.f) + xval;
            v[ct] = tv;
            ss += tv * tv;
        }
        ss += __shfl_xor(ss, 1, 64);
        ss += __shfl_xor(ss, 2, 64);
        ss += __shfl_xor(ss, 4, 64);
        ss += __shfl_xor(ss, 8, 64);
        const float inv = 1.f / fmaxf(sqrtf(ss), 1e-12f);
        if (row < a.N) {
            #pragma unroll
            for (int ct = 0; ct < 8; ++ct) {
                const int col = ct * 16 + lr;
                const float ov = v[ct] * inv;
                if (a.outf) a.outf[(size_t)row * DIM + col] = ov;
                if (a.outh) a.outh[(size_t)row * DIM + col] = (_Float16)ov;
            }
        }
    }
}

// ---------------- launch ----------------

static inline size_t align_up(size_t v, size_t a) { return (v + a - 1) & ~(a - 1); }

extern "C" void kernel_launch(void* const* d_in, const int* in_sizes, int n_in,
                              void* d_out, int out_size, void* d_ws, size_t ws_size,
                              hipStream_t stream) {
    const float* x        = (const float*)d_in[0];
    const int* edge_index = (const int*)d_in[1];
    const int* edge_hop   = (const int*)d_in[2];
    const int* edge_type  = (const int*)d_in[3];
    const float* W_edge   = (const float*)d_in[4];
    const float* b_edge   = (const float*)d_in[5];
    const float* W_hop    = (const float*)d_in[6];
    const float* b_hop    = (const float*)d_in[7];
    float* out = (float*)d_out;

    int N = in_sizes[0] / DIM;   // 50000
    int E = in_sizes[2];         // 600000
    const int* srcA = edge_index;
    const int* dstA = edge_index + E;

    size_t NSh = (size_t)N * DIM * sizeof(_Float16);
    size_t off = 0;
    char* wsb = (char*)d_ws;
    _Float16* xh0     = (_Float16*)(wsb + off);  off = align_up(off + NSh, 64);
    _Float16* xh1     = (_Float16*)(wsb + off);  off = align_up(off + NSh, 64);
    _Float16* xh2     = (_Float16*)(wsb + off);  off = align_up(off + NSh, 64);
    _Float16* xh3     = (_Float16*)(wsb + off);  off = align_up(off + NSh, 64);
    _Float16* A       = (_Float16*)(wsb + off);  off = align_up(off + 7 * NSh, 64);
    _Float16* Wt      = (_Float16*)(wsb + off);  off = align_up(off + 13 * DIM * DIM * sizeof(_Float16), 64);
    int* counts       = (int*)(wsb + off);       off = align_up(off + (size_t)N * 4, 64);
    int* partial      = (int*)(wsb + off);       off = align_up(off + (size_t)N * 4, 64);
    int* blockSums    = (int*)(wsb + off);       off = align_up(off + 64 * 4, 64);
    int* row_ptr      = (int*)(wsb + off);       off = align_up(off + (size_t)(N + 1) * 4, 64);
    int* cursor       = (int*)(wsb + off);       off = align_up(off + (size_t)(N + 1) * 4, 64);
    unsigned* csr     = (unsigned*)(wsb + off);  off = align_up(off + (size_t)E * 4, 64);
    float* bias_sums  = (float*)(wsb + off);     off = align_up(off + 4 * DIM * 4, 64);
    (void)ws_size;  // ~146 MB

    // CSR build
    hipMemsetAsync(counts, 0, (size_t)N * 4, stream);
    k_count<<<(E + 255) / 256, 256, 0, stream>>>(dstA, E, counts);
    int nb = (N + 1023) / 1024;
    k_scan1<<<nb, 1024, 0, stream>>>(counts, N, partial, blockSums);
    k_scan2<<<1, 64, 0, stream>>>(blockSums, nb);
    k_scan3<<<nb, 1024, 0, stream>>>(partial, blockSums, N, row_ptr, cursor);
    k_scatter<<<(E + 255) / 256, 256, 0, stream>>>(srcA, dstA, edge_type, edge_hop, E, cursor, csr);
    k_bias<<<4, DIM, 0, stream>>>(b_edge, b_hop, bias_sums);

    // f16 conversions
    k_convX<<<(N * DIM / 8 + 255) / 256, 256, 0, stream>>>(x, xh0, N * DIM);
    k_convW<<<13, 256, 0, stream>>>(W_edge, W_hop, Wt);

    _Float16* xh_ptr[4] = { xh0, xh1, xh2, xh3 };

    for (int t = 0; t < NLAYER; ++t) {
        GatherArgs g;
        g.xt  = xh_ptr[t];
        g.xm1 = (t >= 1) ? xh_ptr[t - 1] : xh0;
        g.xm2 = (t >= 2) ? xh_ptr[t - 2] : xh0;
        g.xm3 = (t >= 3) ? xh_ptr[t - 3] : xh0;
        g.A = A; g.row_ptr = row_ptr; g.csr = csr; g.t = t; g.N = N;
        k_gather<<<(N + 3) / 4, 256, 0, stream>>>(g);

        GemmArgs m;
        m.A = A; m.Wt = Wt; m.xin = xh_ptr[t];
        m.bias = bias_sums + t * DIM;
        m.outf = (t == 3) ? out : nullptr;
        m.outh = (t < 3) ? xh_ptr[t + 1] : nullptr;
        m.nsub = t + 4; m.N = N;
        int base = t * (t + 1) / 2;
        for (int s = 0; s < 3; ++s) m.wsel[s] = s;
        for (int j = 0; j <= t; ++j) m.wsel[3 + j] = 3 + base + j;
        for (int s = m.nsub; s < 7; ++s) m.wsel[s] = 0;
        k_gemm<<<(N + 63) / 64, 256, 0, stream>>>(m);
    }
}

// Round 6
// 535.524 us; speedup vs baseline: 1.2512x; 1.2512x over previous
//
#include <hip/hip_runtime.h>
#include <hip/hip_bf16.h>

#define DIM 128
#define NLAYER 4

typedef _Float16 f16x8 __attribute__((ext_vector_type(8)));
typedef _Float16 f16x2 __attribute__((ext_vector_type(2)));
typedef float f32x4 __attribute__((ext_vector_type(4)));

// ---------------- CSR build ----------------

__global__ void k_count(const int* __restrict__ dst, int E, int* __restrict__ counts) {
    int e = blockIdx.x * blockDim.x + threadIdx.x;
    if (e < E) atomicAdd(&counts[dst[e]], 1);
}

__global__ __launch_bounds__(1024) void k_scan1(const int* __restrict__ in, int n,
                                                int* __restrict__ partial,
                                                int* __restrict__ blockSums) {
    __shared__ int sd[1024];
    int tid = threadIdx.x;
    int i = blockIdx.x * 1024 + tid;
    int v = (i < n) ? in[i] : 0;
    sd[tid] = v;
    __syncthreads();
    for (int off = 1; off < 1024; off <<= 1) {
        int t = (tid >= off) ? sd[tid - off] : 0;
        __syncthreads();
        sd[tid] += t;
        __syncthreads();
    }
    if (i < n) partial[i] = sd[tid];
    if (tid == 1023) blockSums[blockIdx.x] = sd[1023];
}

__global__ void k_scan2(int* __restrict__ bs, int nb) {
    int lane = threadIdx.x;
    int v = (lane < nb) ? bs[lane] : 0;
    for (int off = 1; off < 64; off <<= 1) {
        int t = __shfl_up(v, off, 64);
        if (lane >= off) v += t;
    }
    int ex = __shfl_up(v, 1, 64);
    if (lane == 0) ex = 0;
    if (lane < nb) bs[lane] = ex;
}

__global__ __launch_bounds__(1024) void k_scan3(const int* __restrict__ partial,
                                                const int* __restrict__ bs, int n,
                                                int* __restrict__ row_ptr,
                                                int* __restrict__ cursor) {
    int i = blockIdx.x * blockDim.x + threadIdx.x;
    if (i < n) {
        int v = partial[i] + bs[i >> 10];
        row_ptr[i + 1] = v;
        cursor[i + 1] = v;
    }
    if (i == 0) { row_ptr[0] = 0; cursor[0] = 0; }
}

__global__ void k_scatter(const int* __restrict__ srcA, const int* __restrict__ dstA,
                          const int* __restrict__ typA, const int* __restrict__ hopA,
                          int E, int* __restrict__ cursor, unsigned* __restrict__ csr) {
    int e = blockIdx.x * blockDim.x + threadIdx.x;
    if (e < E) {
        int d = dstA[e];
        int p = atomicAdd(&cursor[d], 1);
        csr[p] = (unsigned)srcA[e] | ((unsigned)typA[e] << 16) | ((unsigned)hopA[e] << 18);
    }
}

__global__ void k_bias(const float* __restrict__ b_edge, const float* __restrict__ b_hop,
                       float* __restrict__ bias_sums) {
    int t = blockIdx.x, d = threadIdx.x;
    float s = b_edge[d] + b_edge[DIM + d] + b_edge[2 * DIM + d];
    int base = t * (t + 1) / 2;
    for (int k = 1; k <= t + 1; ++k) s += b_hop[(base + k - 1) * DIM + d];
    bias_sums[t * DIM + d] = s;
}

// ---------------- f16 conversions ----------------

__global__ void k_convX(const float* __restrict__ in, _Float16* __restrict__ out, int n) {
    int i = (blockIdx.x * blockDim.x + threadIdx.x) * 8;
    if (i >= n) return;
    float4 a = ((const float4*)(in + i))[0];
    float4 b = ((const float4*)(in + i))[1];
    f16x8 o;
    o[0] = (_Float16)a.x; o[1] = (_Float16)a.y; o[2] = (_Float16)a.z; o[3] = (_Float16)a.w;
    o[4] = (_Float16)b.x; o[5] = (_Float16)b.y; o[6] = (_Float16)b.z; o[7] = (_Float16)b.w;
    *(f16x8*)(out + i) = o;
}

// 13 weight matrices, fp32 row-major [k][n] -> f16 transposed [n][k]
__global__ __launch_bounds__(256) void k_convW(const float* __restrict__ W_edge,
                                               const float* __restrict__ W_hop,
                                               _Float16* __restrict__ Wt) {
    int s = blockIdx.x;
    const float* src = (s < 3) ? (W_edge + (size_t)s * DIM * DIM)
                               : (W_hop + (size_t)(s - 3) * DIM * DIM);
    _Float16* dstp = Wt + (size_t)s * DIM * DIM;
    for (int it = 0; it < 64; ++it) {
        int e = it * 256 + threadIdx.x;
        int n = e >> 7, k = e & 127;
        dstp[e] = (_Float16)src[k * DIM + n];
    }
}

// -------- phase 1: CSR gather-aggregate, 4-edge unrolled for MLP --------
// A slot map: 0..2 = edge types, 3+(k-1) = hop k

struct GatherArgs {
    const _Float16* xt;    // xh[t]   (types + hop1)
    const _Float16* xm1;   // xh[t-1] (hop2)
    const _Float16* xm2;   // xh[t-2] (hop3)
    const _Float16* xm3;   // xh[t-3] (hop4)
    _Float16* A;           // [7][N][128]
    const int* row_ptr;
    const unsigned* csr;
    int t, N;
};

__global__ __launch_bounds__(256) void k_gather(GatherArgs a) {
    const int wid = threadIdx.x >> 6, lane = threadIdx.x & 63;
    const int node = blockIdx.x * 4 + wid;   // one node per wave
    if (node >= a.N) return;
    const size_t NS = (size_t)a.N * DIM;
    const int hopMax = a.t + 1;

    float t0x = 0, t0y = 0, t1x = 0, t1y = 0, t2x = 0, t2y = 0;
    float h1x = 0, h1y = 0, h2x = 0, h2y = 0, h3x = 0, h3y = 0, h4x = 0, h4y = 0;

    const int e0 = a.row_ptr[node], e1 = a.row_ptr[node + 1];
    int e = e0;
    const int e4 = e0 + ((e1 - e0) & ~3);

    // 4-edge unroll: batch 8 row-loads in flight, then wave-uniform accumulate.
    for (; e < e4; e += 4) {
        unsigned mm[4];
        #pragma unroll
        for (int j = 0; j < 4; ++j) mm[j] = a.csr[e + j];
        f16x2 vv[4], ww[4];
        #pragma unroll
        for (int j = 0; j < 4; ++j) {
            const int src = mm[j] & 0xFFFF;
            const int hop = (int)(mm[j] >> 18);
            vv[j] = ((const f16x2*)(a.xt + (size_t)src * DIM))[lane];
            // inactive/hop<=1 aliases the type row -> L1 hit, no extra L2 traffic
            const _Float16* ph =
                (hop == 2 && hopMax >= 2) ? a.xm1 :
                (hop == 3 && hopMax >= 3) ? a.xm2 :
                (hop == 4 && hopMax >= 4) ? a.xm3 : a.xt;
            ww[j] = ((const f16x2*)(ph + (size_t)src * DIM))[lane];
        }
        #pragma unroll
        for (int j = 0; j < 4; ++j) {
            const int typ = (mm[j] >> 16) & 3;
            const int hop = (int)(mm[j] >> 18);
            const float vx = (float)vv[j][0], vy = (float)vv[j][1];
            if (typ == 0)      { t0x += vx; t0y += vy; }   // wave-uniform branches
            else if (typ == 1) { t1x += vx; t1y += vy; }
            else               { t2x += vx; t2y += vy; }
            if (hop >= 1 && hop <= hopMax) {
                const float wx = (float)ww[j][0], wy = (float)ww[j][1];
                if (hop == 1)      { h1x += wx; h1y += wy; }
                else if (hop == 2) { h2x += wx; h2y += wy; }
                else if (hop == 3) { h3x += wx; h3y += wy; }
                else               { h4x += wx; h4y += wy; }
            }
        }
    }
    for (; e < e1; ++e) {
        const unsigned m = a.csr[e];
        const int src = m & 0xFFFF;
        const int typ = (m >> 16) & 3;
        const int hop = (int)(m >> 18);
        const f16x2 v = ((const f16x2*)(a.xt + (size_t)src * DIM))[lane];
        const float vx = (float)v[0], vy = (float)v[1];
        if (typ == 0)      { t0x += vx; t0y += vy; }
        else if (typ == 1) { t1x += vx; t1y += vy; }
        else               { t2x += vx; t2y += vy; }
        if (hop >= 1 && hop <= hopMax) {
            const _Float16* ph = (hop == 2) ? a.xm1 : (hop == 3) ? a.xm2 :
                                 (hop == 4) ? a.xm3 : a.xt;
            const f16x2 w = ((const f16x2*)(ph + (size_t)src * DIM))[lane];
            const float wx = (float)w[0], wy = (float)w[1];
            if (hop == 1)      { h1x += wx; h1y += wy; }
            else if (hop == 2) { h2x += wx; h2y += wy; }
            else if (hop == 3) { h3x += wx; h3y += wy; }
            else               { h4x += wx; h4y += wy; }
        }
    }

    _Float16* base = a.A + (size_t)node * DIM;
    f16x2 o;
    o[0] = (_Float16)t0x; o[1] = (_Float16)t0y; ((f16x2*)(base + 0 * NS))[lane] = o;
    o[0] = (_Float16)t1x; o[1] = (_Float16)t1y; ((f16x2*)(base + 1 * NS))[lane] = o;
    o[0] = (_Float16)t2x; o[1] = (_Float16)t2y; ((f16x2*)(base + 2 * NS))[lane] = o;
    o[0] = (_Float16)h1x; o[1] = (_Float16)h1y; ((f16x2*)(base + 3 * NS))[lane] = o;
    if (a.t >= 1) { o[0] = (_Float16)h2x; o[1] = (_Float16)h2y; ((f16x2*)(base + 4 * NS))[lane] = o; }
    if (a.t >= 2) { o[0] = (_Float16)h3x; o[1] = (_Float16)h3y; ((f16x2*)(base + 5 * NS))[lane] = o; }
    if (a.t >= 3) { o[0] = (_Float16)h4x; o[1] = (_Float16)h4y; ((f16x2*)(base + 6 * NS))[lane] = o; }
}

// -------- phase 2: C = sum_s A_s @ W_s, fused bias+relu+residual+L2norm --------
// wave = 32 rows x 128 cols (R3 shape, af[2] amortization); block = 2 waves = 64
// rows -> grid 782 (~3 blocks/CU, balanced). NSUB compile-time for full unroll.

struct GemmArgs {
    const _Float16* A;     // [7][N][128]
    const _Float16* Wt;    // 13 x [n][k] f16
    const _Float16* xin;   // xh[t], residual source
    const float* bias;     // bias_sums + t*128
    float* outf;           // fp32 out (final layer) or null
    _Float16* outh;        // xh[t+1] or null
    int nsub, N;
    int wsel[7];
};

template <int NSUB>
__global__ __launch_bounds__(128, 2) void k_gemm(GemmArgs a) {
    const int wv = threadIdx.x >> 6, lane = threadIdx.x & 63;
    const int rowBase = blockIdx.x * 64 + wv * 32;
    const int lr = lane & 15, lg = lane >> 4;
    const size_t NS = (size_t)a.N * DIM;

    f32x4 acc[2][8];
    #pragma unroll
    for (int rt = 0; rt < 2; ++rt)
        #pragma unroll
        for (int ct = 0; ct < 8; ++ct)
            acc[rt][ct] = (f32x4){0.f, 0.f, 0.f, 0.f};

    int r0 = rowBase + lr;
    int r1 = rowBase + 16 + lr;
    if (r0 >= a.N) r0 = a.N - 1;
    if (r1 >= a.N) r1 = a.N - 1;

    #pragma unroll
    for (int s = 0; s < NSUB; ++s) {
        const _Float16* As = a.A + (size_t)s * NS;
        const _Float16* Bs = a.Wt + (size_t)a.wsel[s] * (DIM * DIM);
        #pragma unroll
        for (int ks = 0; ks < 4; ++ks) {
            const int kb = ks * 32 + lg * 8;
            const f16x8 a0 = *(const f16x8*)(As + (size_t)r0 * DIM + kb);
            const f16x8 a1 = *(const f16x8*)(As + (size_t)r1 * DIM + kb);
            #pragma unroll
            for (int ct = 0; ct < 8; ++ct) {
                const f16x8 bf = *(const f16x8*)(Bs + (size_t)(ct * 16 + lr) * DIM + kb);
                acc[0][ct] = __builtin_amdgcn_mfma_f32_16x16x32_f16(a0, bf, acc[0][ct], 0, 0, 0);
                acc[1][ct] = __builtin_amdgcn_mfma_f32_16x16x32_f16(a1, bf, acc[1][ct], 0, 0, 0);
            }
        }
    }

    float bv[8];
    #pragma unroll
    for (int ct = 0; ct < 8; ++ct) bv[ct] = a.bias[ct * 16 + lr];

    // C/D layout: col = lane&15, row = (lane>>4)*4 + reg
    #pragma unroll
    for (int rt = 0; rt < 2; ++rt) {
        #pragma unroll
        for (int rg = 0; rg < 4; ++rg) {
            const int row = rowBase + rt * 16 + lg * 4 + rg;
            const int rr = (row < a.N) ? row : a.N - 1;
            float v[8];
            float ss = 0.f;
            #pragma unroll
            for (int ct = 0; ct < 8; ++ct) {
                const float xval = (float)a.xin[(size_t)rr * DIM + ct * 16 + lr];
                const float tv = fmaxf(acc[rt][ct][rg] + bv[ct], 0.f) + xval;
                v[ct] = tv;
                ss += tv * tv;
            }
            ss += __shfl_xor(ss, 1, 64);
            ss += __shfl_xor(ss, 2, 64);
            ss += __shfl_xor(ss, 4, 64);
            ss += __shfl_xor(ss, 8, 64);
            const float inv = 1.f / fmaxf(sqrtf(ss), 1e-12f);
            if (row < a.N) {
                #pragma unroll
                for (int ct = 0; ct < 8; ++ct) {
                    const int col = ct * 16 + lr;
                    const float ov = v[ct] * inv;
                    if (a.outf) a.outf[(size_t)row * DIM + col] = ov;
                    if (a.outh) a.outh[(size_t)row * DIM + col] = (_Float16)ov;
                }
            }
        }
    }
}

// ---------------- launch ----------------

static inline size_t align_up(size_t v, size_t a) { return (v + a - 1) & ~(a - 1); }

extern "C" void kernel_launch(void* const* d_in, const int* in_sizes, int n_in,
                              void* d_out, int out_size, void* d_ws, size_t ws_size,
                              hipStream_t stream) {
    const float* x        = (const float*)d_in[0];
    const int* edge_index = (const int*)d_in[1];
    const int* edge_hop   = (const int*)d_in[2];
    const int* edge_type  = (const int*)d_in[3];
    const float* W_edge   = (const float*)d_in[4];
    const float* b_edge   = (const float*)d_in[5];
    const float* W_hop    = (const float*)d_in[6];
    const float* b_hop    = (const float*)d_in[7];
    float* out = (float*)d_out;

    int N = in_sizes[0] / DIM;   // 50000
    int E = in_sizes[2];         // 600000
    const int* srcA = edge_index;
    const int* dstA = edge_index + E;

    size_t NSh = (size_t)N * DIM * sizeof(_Float16);
    size_t off = 0;
    char* wsb = (char*)d_ws;
    _Float16* xh0     = (_Float16*)(wsb + off);  off = align_up(off + NSh, 64);
    _Float16* xh1     = (_Float16*)(wsb + off);  off = align_up(off + NSh, 64);
    _Float16* xh2     = (_Float16*)(wsb + off);  off = align_up(off + NSh, 64);
    _Float16* xh3     = (_Float16*)(wsb + off);  off = align_up(off + NSh, 64);
    _Float16* A       = (_Float16*)(wsb + off);  off = align_up(off + 7 * NSh, 64);
    _Float16* Wt      = (_Float16*)(wsb + off);  off = align_up(off + 13 * DIM * DIM * sizeof(_Float16), 64);
    int* counts       = (int*)(wsb + off);       off = align_up(off + (size_t)N * 4, 64);
    int* partial      = (int*)(wsb + off);       off = align_up(off + (size_t)N * 4, 64);
    int* blockSums    = (int*)(wsb + off);       off = align_up(off + 64 * 4, 64);
    int* row_ptr      = (int*)(wsb + off);       off = align_up(off + (size_t)(N + 1) * 4, 64);
    int* cursor       = (int*)(wsb + off);       off = align_up(off + (size_t)(N + 1) * 4, 64);
    unsigned* csr     = (unsigned*)(wsb + off);  off = align_up(off + (size_t)E * 4, 64);
    float* bias_sums  = (float*)(wsb + off);     off = align_up(off + 4 * DIM * 4, 64);
    (void)ws_size;  // ~146 MB

    // CSR build
    hipMemsetAsync(counts, 0, (size_t)N * 4, stream);
    k_count<<<(E + 255) / 256, 256, 0, stream>>>(dstA, E, counts);
    int nb = (N + 1023) / 1024;
    k_scan1<<<nb, 1024, 0, stream>>>(counts, N, partial, blockSums);
    k_scan2<<<1, 64, 0, stream>>>(blockSums, nb);
    k_scan3<<<nb, 1024, 0, stream>>>(partial, blockSums, N, row_ptr, cursor);
    k_scatter<<<(E + 255) / 256, 256, 0, stream>>>(srcA, dstA, edge_type, edge_hop, E, cursor, csr);
    k_bias<<<4, DIM, 0, stream>>>(b_edge, b_hop, bias_sums);

    // f16 conversions
    k_convX<<<(N * DIM / 8 + 255) / 256, 256, 0, stream>>>(x, xh0, N * DIM);
    k_convW<<<13, 256, 0, stream>>>(W_edge, W_hop, Wt);

    _Float16* xh_ptr[4] = { xh0, xh1, xh2, xh3 };

    for (int t = 0; t < NLAYER; ++t) {
        GatherArgs g;
        g.xt  = xh_ptr[t];
        g.xm1 = (t >= 1) ? xh_ptr[t - 1] : xh0;
        g.xm2 = (t >= 2) ? xh_ptr[t - 2] : xh0;
        g.xm3 = (t >= 3) ? xh_ptr[t - 3] : xh0;
        g.A = A; g.row_ptr = row_ptr; g.csr = csr; g.t = t; g.N = N;
        k_gather<<<(N + 3) / 4, 256, 0, stream>>>(g);

        GemmArgs m;
        m.A = A; m.Wt = Wt; m.xin = xh_ptr[t];
        m.bias = bias_sums + t * DIM;
        m.outf = (t == 3) ? out : nullptr;
        m.outh = (t < 3) ? xh_ptr[t + 1] : nullptr;
        m.nsub = t + 4; m.N = N;
        int base = t * (t + 1) / 2;
        for (int s = 0; s < 3; ++s) m.wsel[s] = s;
        for (int j = 0; j <= t; ++j) m.wsel[3 + j] = 3 + base + j;
        for (int s = m.nsub; s < 7; ++s) m.wsel[s] = 0;

        const int gb = (N + 63) / 64;
        switch (m.nsub) {
            case 4: k_gemm<4><<<gb, 128, 0, stream>>>(m); break;
            case 5: k_gemm<5><<<gb, 128, 0, stream>>>(m); break;
            case 6: k_gemm<6><<<gb, 128, 0, stream>>>(m); break;
            default: k_gemm<7><<<gb, 128, 0, stream>>>(m); break;
        }
    }
}

// Round 7
// 406.749 us; speedup vs baseline: 1.6474x; 1.3166x over previous
//
#include <hip/hip_runtime.h>
#include <hip/hip_bf16.h>

#define DIM 128
#define NLAYER 4

typedef _Float16 f16x8 __attribute__((ext_vector_type(8)));
typedef _Float16 f16x2 __attribute__((ext_vector_type(2)));
typedef float f32x4 __attribute__((ext_vector_type(4)));

// ---------------- CSR build ----------------

__global__ void k_count(const int* __restrict__ dst, int E, int* __restrict__ counts) {
    int e = blockIdx.x * blockDim.x + threadIdx.x;
    if (e < E) atomicAdd(&counts[dst[e]], 1);
}

__global__ __launch_bounds__(1024) void k_scan1(const int* __restrict__ in, int n,
                                                int* __restrict__ partial,
                                                int* __restrict__ blockSums) {
    __shared__ int sd[1024];
    int tid = threadIdx.x;
    int i = blockIdx.x * 1024 + tid;
    int v = (i < n) ? in[i] : 0;
    sd[tid] = v;
    __syncthreads();
    for (int off = 1; off < 1024; off <<= 1) {
        int t = (tid >= off) ? sd[tid - off] : 0;
        __syncthreads();
        sd[tid] += t;
        __syncthreads();
    }
    if (i < n) partial[i] = sd[tid];
    if (tid == 1023) blockSums[blockIdx.x] = sd[1023];
}

__global__ void k_scan2(int* __restrict__ bs, int nb) {
    int lane = threadIdx.x;
    int v = (lane < nb) ? bs[lane] : 0;
    for (int off = 1; off < 64; off <<= 1) {
        int t = __shfl_up(v, off, 64);
        if (lane >= off) v += t;
    }
    int ex = __shfl_up(v, 1, 64);
    if (lane == 0) ex = 0;
    if (lane < nb) bs[lane] = ex;
}

__global__ __launch_bounds__(1024) void k_scan3(const int* __restrict__ partial,
                                                const int* __restrict__ bs, int n,
                                                int* __restrict__ row_ptr,
                                                int* __restrict__ cursor) {
    int i = blockIdx.x * blockDim.x + threadIdx.x;
    if (i < n) {
        int v = partial[i] + bs[i >> 10];
        row_ptr[i + 1] = v;
        cursor[i + 1] = v;
    }
    if (i == 0) { row_ptr[0] = 0; cursor[0] = 0; }
}

__global__ void k_scatter(const int* __restrict__ srcA, const int* __restrict__ dstA,
                          const int* __restrict__ typA, const int* __restrict__ hopA,
                          int E, int* __restrict__ cursor, unsigned* __restrict__ csr) {
    int e = blockIdx.x * blockDim.x + threadIdx.x;
    if (e < E) {
        int d = dstA[e];
        int p = atomicAdd(&cursor[d], 1);
        csr[p] = (unsigned)srcA[e] | ((unsigned)typA[e] << 16) | ((unsigned)hopA[e] << 18);
    }
}

__global__ void k_bias(const float* __restrict__ b_edge, const float* __restrict__ b_hop,
                       float* __restrict__ bias_sums) {
    int t = blockIdx.x, d = threadIdx.x;
    float s = b_edge[d] + b_edge[DIM + d] + b_edge[2 * DIM + d];
    int base = t * (t + 1) / 2;
    for (int k = 1; k <= t + 1; ++k) s += b_hop[(base + k - 1) * DIM + d];
    bias_sums[t * DIM + d] = s;
}

// ---------------- f16 conversions ----------------

__global__ void k_convX(const float* __restrict__ in, _Float16* __restrict__ out, int n) {
    int i = (blockIdx.x * blockDim.x + threadIdx.x) * 8;
    if (i >= n) return;
    float4 a = ((const float4*)(in + i))[0];
    float4 b = ((const float4*)(in + i))[1];
    f16x8 o;
    o[0] = (_Float16)a.x; o[1] = (_Float16)a.y; o[2] = (_Float16)a.z; o[3] = (_Float16)a.w;
    o[4] = (_Float16)b.x; o[5] = (_Float16)b.y; o[6] = (_Float16)b.z; o[7] = (_Float16)b.w;
    *(f16x8*)(out + i) = o;
}

// 13 weight matrices, fp32 row-major [k][n] -> f16 transposed [n][k]
__global__ __launch_bounds__(256) void k_convW(const float* __restrict__ W_edge,
                                               const float* __restrict__ W_hop,
                                               _Float16* __restrict__ Wt) {
    int s = blockIdx.x;
    const float* src = (s < 3) ? (W_edge + (size_t)s * DIM * DIM)
                               : (W_hop + (size_t)(s - 3) * DIM * DIM);
    _Float16* dstp = Wt + (size_t)s * DIM * DIM;
    for (int it = 0; it < 64; ++it) {
        int e = it * 256 + threadIdx.x;
        int n = e >> 7, k = e & 127;
        dstp[e] = (_Float16)src[k * DIM + n];
    }
}

// -------- phase 1: CSR gather-aggregate, 4-edge unrolled for MLP --------
// A slot map: 0..2 = edge types, 3+(k-1) = hop k

struct GatherArgs {
    const _Float16* xt;    // xh[t]   (types + hop1)
    const _Float16* xm1;   // xh[t-1] (hop2)
    const _Float16* xm2;   // xh[t-2] (hop3)
    const _Float16* xm3;   // xh[t-3] (hop4)
    _Float16* A;           // [7][N][128]
    const int* row_ptr;
    const unsigned* csr;
    int t, N;
};

__global__ __launch_bounds__(256) void k_gather(GatherArgs a) {
    const int wid = threadIdx.x >> 6, lane = threadIdx.x & 63;
    const int node = blockIdx.x * 4 + wid;   // one node per wave
    if (node >= a.N) return;
    const size_t NS = (size_t)a.N * DIM;
    const int hopMax = a.t + 1;

    float t0x = 0, t0y = 0, t1x = 0, t1y = 0, t2x = 0, t2y = 0;
    float h1x = 0, h1y = 0, h2x = 0, h2y = 0, h3x = 0, h3y = 0, h4x = 0, h4y = 0;

    const int e0 = a.row_ptr[node], e1 = a.row_ptr[node + 1];
    int e = e0;
    const int e4 = e0 + ((e1 - e0) & ~3);

    // 4-edge unroll: batch 8 row-loads in flight, then wave-uniform accumulate.
    for (; e < e4; e += 4) {
        unsigned mm[4];
        #pragma unroll
        for (int j = 0; j < 4; ++j) mm[j] = a.csr[e + j];
        f16x2 vv[4], ww[4];
        #pragma unroll
        for (int j = 0; j < 4; ++j) {
            const int src = mm[j] & 0xFFFF;
            const int hop = (int)(mm[j] >> 18);
            vv[j] = ((const f16x2*)(a.xt + (size_t)src * DIM))[lane];
            // inactive/hop<=1 aliases the type row -> L1 hit, no extra L2 traffic
            const _Float16* ph =
                (hop == 2 && hopMax >= 2) ? a.xm1 :
                (hop == 3 && hopMax >= 3) ? a.xm2 :
                (hop == 4 && hopMax >= 4) ? a.xm3 : a.xt;
            ww[j] = ((const f16x2*)(ph + (size_t)src * DIM))[lane];
        }
        #pragma unroll
        for (int j = 0; j < 4; ++j) {
            const int typ = (mm[j] >> 16) & 3;
            const int hop = (int)(mm[j] >> 18);
            const float vx = (float)vv[j][0], vy = (float)vv[j][1];
            if (typ == 0)      { t0x += vx; t0y += vy; }   // wave-uniform branches
            else if (typ == 1) { t1x += vx; t1y += vy; }
            else               { t2x += vx; t2y += vy; }
            if (hop >= 1 && hop <= hopMax) {
                const float wx = (float)ww[j][0], wy = (float)ww[j][1];
                if (hop == 1)      { h1x += wx; h1y += wy; }
                else if (hop == 2) { h2x += wx; h2y += wy; }
                else if (hop == 3) { h3x += wx; h3y += wy; }
                else               { h4x += wx; h4y += wy; }
            }
        }
    }
    for (; e < e1; ++e) {
        const unsigned m = a.csr[e];
        const int src = m & 0xFFFF;
        const int typ = (m >> 16) & 3;
        const int hop = (int)(m >> 18);
        const f16x2 v = ((const f16x2*)(a.xt + (size_t)src * DIM))[lane];
        const float vx = (float)v[0], vy = (float)v[1];
        if (typ == 0)      { t0x += vx; t0y += vy; }
        else if (typ == 1) { t1x += vx; t1y += vy; }
        else               { t2x += vx; t2y += vy; }
        if (hop >= 1 && hop <= hopMax) {
            const _Float16* ph = (hop == 2) ? a.xm1 : (hop == 3) ? a.xm2 :
                                 (hop == 4) ? a.xm3 : a.xt;
            const f16x2 w = ((const f16x2*)(ph + (size_t)src * DIM))[lane];
            const float wx = (float)w[0], wy = (float)w[1];
            if (hop == 1)      { h1x += wx; h1y += wy; }
            else if (hop == 2) { h2x += wx; h2y += wy; }
            else if (hop == 3) { h3x += wx; h3y += wy; }
            else               { h4x += wx; h4y += wy; }
        }
    }

    _Float16* base = a.A + (size_t)node * DIM;
    f16x2 o;
    o[0] = (_Float16)t0x; o[1] = (_Float16)t0y; ((f16x2*)(base + 0 * NS))[lane] = o;
    o[0] = (_Float16)t1x; o[1] = (_Float16)t1y; ((f16x2*)(base + 1 * NS))[lane] = o;
    o[0] = (_Float16)t2x; o[1] = (_Float16)t2y; ((f16x2*)(base + 2 * NS))[lane] = o;
    o[0] = (_Float16)h1x; o[1] = (_Float16)h1y; ((f16x2*)(base + 3 * NS))[lane] = o;
    if (a.t >= 1) { o[0] = (_Float16)h2x; o[1] = (_Float16)h2y; ((f16x2*)(base + 4 * NS))[lane] = o; }
    if (a.t >= 2) { o[0] = (_Float16)h3x; o[1] = (_Float16)h3y; ((f16x2*)(base + 5 * NS))[lane] = o; }
    if (a.t >= 3) { o[0] = (_Float16)h4x; o[1] = (_Float16)h4y; ((f16x2*)(base + 6 * NS))[lane] = o; }
}

// -------- phase 2: C = sum_s A_s @ W_s, fused bias+relu+residual+L2norm --------
// W_s staged in LDS (XOR-swizzled, G21: swizzled store + swizzled read), A and
// next-W prefetched into registers before each compute phase (T3 2-phase).

struct GemmArgs {
    const _Float16* A;     // [7][N][128]
    const _Float16* Wt;    // 13 x [n][k] f16
    const _Float16* xin;   // xh[t], residual source
    const float* bias;     // bias_sums + t*128
    float* outf;           // fp32 out (final layer) or null
    _Float16* outh;        // xh[t+1] or null
    int nsub, N;
    int wsel[7];
};

template <int NSUB>
__global__ __launch_bounds__(128, 2) void k_gemm(GemmArgs a) {
    __shared__ __align__(16) _Float16 Wlds[DIM * DIM];   // 32 KB, swizzled
    const int tid = threadIdx.x, wv = tid >> 6, lane = tid & 63;
    const int rowBase = blockIdx.x * 64 + wv * 32;
    const int lr = lane & 15, lg = lane >> 4;
    const size_t NS = (size_t)a.N * DIM;

    int r0 = rowBase + lr, r1 = rowBase + 16 + lr;
    if (r0 >= a.N) r0 = a.N - 1;
    if (r1 >= a.N) r1 = a.N - 1;

    f32x4 acc[2][8];
    #pragma unroll
    for (int rt = 0; rt < 2; ++rt)
        #pragma unroll
        for (int ct = 0; ct < 8; ++ct)
            acc[rt][ct] = (f32x4){0.f, 0.f, 0.f, 0.f};

    const int sw = (lr & 7) << 4;   // read-side XOR (bits 4-6 of byte addr)

    // ---- prologue: stage W[wsel[0]] -> LDS (swizzled), prefetch A frags s=0
    {
        const _Float16* Ws = a.Wt + (size_t)a.wsel[0] * (DIM * DIM);
        f16x8 w[16];
        #pragma unroll
        for (int i = 0; i < 16; ++i)
            w[i] = *(const f16x8*)((const char*)Ws + i * 2048 + tid * 16);
        #pragma unroll
        for (int i = 0; i < 16; ++i) {
            const int p = i * 2048 + tid * 16;
            const int q = p ^ (((p >> 8) & 7) << 4);
            *(f16x8*)((char*)Wlds + q) = w[i];
        }
    }
    f16x8 afA[2][4], afB[2][4];
    #pragma unroll
    for (int ks = 0; ks < 4; ++ks) {
        afA[0][ks] = *(const f16x8*)(a.A + (size_t)r0 * DIM + ks * 32 + lg * 8);
        afB[0][ks] = *(const f16x8*)(a.A + (size_t)r1 * DIM + ks * 32 + lg * 8);
    }
    __syncthreads();

    #pragma unroll
    for (int s = 0; s < NSUB; ++s) {
        const int cur = s & 1, nxt = cur ^ 1;
        // prefetch next W into regs + next A frags (land during compute;
        // the pre-barrier vmcnt drain guarantees residency at ds_write time)
        f16x8 w[16];
        if (s + 1 < NSUB) {
            const _Float16* Wn = a.Wt + (size_t)a.wsel[s + 1] * (DIM * DIM);
            #pragma unroll
            for (int i = 0; i < 16; ++i)
                w[i] = *(const f16x8*)((const char*)Wn + i * 2048 + tid * 16);
            const _Float16* An = a.A + (size_t)(s + 1) * NS;
            #pragma unroll
            for (int ks = 0; ks < 4; ++ks) {
                afA[nxt][ks] = *(const f16x8*)(An + (size_t)r0 * DIM + ks * 32 + lg * 8);
                afB[nxt][ks] = *(const f16x8*)(An + (size_t)r1 * DIM + ks * 32 + lg * 8);
            }
        }
        // compute s: B fragments from LDS
        #pragma unroll
        for (int ks = 0; ks < 4; ++ks) {
            const int cb = (ks * 32 + lg * 8) * 2;
            #pragma unroll
            for (int ct = 0; ct < 8; ++ct) {
                const int addr = (ct * 16 + lr) * 256 + (cb ^ sw);
                const f16x8 bf = *(const f16x8*)((const char*)Wlds + addr);
                acc[0][ct] = __builtin_amdgcn_mfma_f32_16x16x32_f16(afA[cur][ks], bf, acc[0][ct], 0, 0, 0);
                acc[1][ct] = __builtin_amdgcn_mfma_f32_16x16x32_f16(afB[cur][ks], bf, acc[1][ct], 0, 0, 0);
            }
        }
        __syncthreads();   // all waves done reading Wlds(s)
        if (s + 1 < NSUB) {
            #pragma unroll
            for (int i = 0; i < 16; ++i) {
                const int p = i * 2048 + tid * 16;
                const int q = p ^ (((p >> 8) & 7) << 4);
                *(f16x8*)((char*)Wlds + q) = w[i];
            }
            __syncthreads();   // Wlds(s+1) visible
        }
    }

    float bv[8];
    #pragma unroll
    for (int ct = 0; ct < 8; ++ct) bv[ct] = a.bias[ct * 16 + lr];

    // C/D layout: col = lane&15, row = (lane>>4)*4 + reg
    #pragma unroll
    for (int rt = 0; rt < 2; ++rt) {
        #pragma unroll
        for (int rg = 0; rg < 4; ++rg) {
            const int row = rowBase + rt * 16 + lg * 4 + rg;
            const int rr = (row < a.N) ? row : a.N - 1;
            float v[8];
            float ss = 0.f;
            #pragma unroll
            for (int ct = 0; ct < 8; ++ct) {
                const float xval = (float)a.xin[(size_t)rr * DIM + ct * 16 + lr];
                const float tv = fmaxf(acc[rt][ct][rg] + bv[ct], 0.f) + xval;
                v[ct] = tv;
                ss += tv * tv;
            }
            ss += __shfl_xor(ss, 1, 64);
            ss += __shfl_xor(ss, 2, 64);
            ss += __shfl_xor(ss, 4, 64);
            ss += __shfl_xor(ss, 8, 64);
            const float inv = 1.f / fmaxf(sqrtf(ss), 1e-12f);
            if (row < a.N) {
                #pragma unroll
                for (int ct = 0; ct < 8; ++ct) {
                    const int col = ct * 16 + lr;
                    const float ov = v[ct] * inv;
                    if (a.outf) a.outf[(size_t)row * DIM + col] = ov;
                    if (a.outh) a.outh[(size_t)row * DIM + col] = (_Float16)ov;
                }
            }
        }
    }
}

// ---------------- launch ----------------

static inline size_t align_up(size_t v, size_t a) { return (v + a - 1) & ~(a - 1); }

extern "C" void kernel_launch(void* const* d_in, const int* in_sizes, int n_in,
                              void* d_out, int out_size, void* d_ws, size_t ws_size,
                              hipStream_t stream) {
    const float* x        = (const float*)d_in[0];
    const int* edge_index = (const int*)d_in[1];
    const int* edge_hop   = (const int*)d_in[2];
    const int* edge_type  = (const int*)d_in[3];
    const float* W_edge   = (const float*)d_in[4];
    const float* b_edge   = (const float*)d_in[5];
    const float* W_hop    = (const float*)d_in[6];
    const float* b_hop    = (const float*)d_in[7];
    float* out = (float*)d_out;

    int N = in_sizes[0] / DIM;   // 50000
    int E = in_sizes[2];         // 600000
    const int* srcA = edge_index;
    const int* dstA = edge_index + E;

    size_t NSh = (size_t)N * DIM * sizeof(_Float16);
    size_t off = 0;
    char* wsb = (char*)d_ws;
    _Float16* xh0     = (_Float16*)(wsb + off);  off = align_up(off + NSh, 64);
    _Float16* xh1     = (_Float16*)(wsb + off);  off = align_up(off + NSh, 64);
    _Float16* xh2     = (_Float16*)(wsb + off);  off = align_up(off + NSh, 64);
    _Float16* xh3     = (_Float16*)(wsb + off);  off = align_up(off + NSh, 64);
    _Float16* A       = (_Float16*)(wsb + off);  off = align_up(off + 7 * NSh, 64);
    _Float16* Wt      = (_Float16*)(wsb + off);  off = align_up(off + 13 * DIM * DIM * sizeof(_Float16), 64);
    int* counts       = (int*)(wsb + off);       off = align_up(off + (size_t)N * 4, 64);
    int* partial      = (int*)(wsb + off);       off = align_up(off + (size_t)N * 4, 64);
    int* blockSums    = (int*)(wsb + off);       off = align_up(off + 64 * 4, 64);
    int* row_ptr      = (int*)(wsb + off);       off = align_up(off + (size_t)(N + 1) * 4, 64);
    int* cursor       = (int*)(wsb + off);       off = align_up(off + (size_t)(N + 1) * 4, 64);
    unsigned* csr     = (unsigned*)(wsb + off);  off = align_up(off + (size_t)E * 4, 64);
    float* bias_sums  = (float*)(wsb + off);     off = align_up(off + 4 * DIM * 4, 64);
    (void)ws_size;  // ~146 MB

    // CSR build
    hipMemsetAsync(counts, 0, (size_t)N * 4, stream);
    k_count<<<(E + 255) / 256, 256, 0, stream>>>(dstA, E, counts);
    int nb = (N + 1023) / 1024;
    k_scan1<<<nb, 1024, 0, stream>>>(counts, N, partial, blockSums);
    k_scan2<<<1, 64, 0, stream>>>(blockSums, nb);
    k_scan3<<<nb, 1024, 0, stream>>>(partial, blockSums, N, row_ptr, cursor);
    k_scatter<<<(E + 255) / 256, 256, 0, stream>>>(srcA, dstA, edge_type, edge_hop, E, cursor, csr);
    k_bias<<<4, DIM, 0, stream>>>(b_edge, b_hop, bias_sums);

    // f16 conversions
    k_convX<<<(N * DIM / 8 + 255) / 256, 256, 0, stream>>>(x, xh0, N * DIM);
    k_convW<<<13, 256, 0, stream>>>(W_edge, W_hop, Wt);

    _Float16* xh_ptr[4] = { xh0, xh1, xh2, xh3 };

    for (int t = 0; t < NLAYER; ++t) {
        GatherArgs g;
        g.xt  = xh_ptr[t];
        g.xm1 = (t >= 1) ? xh_ptr[t - 1] : xh0;
        g.xm2 = (t >= 2) ? xh_ptr[t - 2] : xh0;
        g.xm3 = (t >= 3) ? xh_ptr[t - 3] : xh0;
        g.A = A; g.row_ptr = row_ptr; g.csr = csr; g.t = t; g.N = N;
        k_gather<<<(N + 3) / 4, 256, 0, stream>>>(g);

        GemmArgs m;
        m.A = A; m.Wt = Wt; m.xin = xh_ptr[t];
        m.bias = bias_sums + t * DIM;
        m.outf = (t == 3) ? out : nullptr;
        m.outh = (t < 3) ? xh_ptr[t + 1] : nullptr;
        m.nsub = t + 4; m.N = N;
        int base = t * (t + 1) / 2;
        for (int s = 0; s < 3; ++s) m.wsel[s] = s;
        for (int j = 0; j <= t; ++j) m.wsel[3 + j] = 3 + base + j;
        for (int s = m.nsub; s < 7; ++s) m.wsel[s] = 0;

        const int gb = (N + 63) / 64;
        switch (m.nsub) {
            case 4: k_gemm<4><<<gb, 128, 0, stream>>>(m); break;
            case 5: k_gemm<5><<<gb, 128, 0, stream>>>(m); break;
            case 6: k_gemm<6><<<gb, 128, 0, stream>>>(m); break;
            default: k_gemm<7><<<gb, 128, 0, stream>>>(m); break;
        }
    }
}

// Round 8
// 388.890 us; speedup vs baseline: 1.7230x; 1.0459x over previous
//
#include <hip/hip_runtime.h>
#include <hip/hip_bf16.h>

#define DIM 128
#define NLAYER 4

typedef _Float16 f16x8 __attribute__((ext_vector_type(8)));
typedef _Float16 f16x2 __attribute__((ext_vector_type(2)));
typedef float f32x4 __attribute__((ext_vector_type(4)));

// ---------------- CSR build (grouped by (dst, hop desc)) ----------------
// group index g = 4 - hop  (hop 4->0, 3->1, 2->2, 1->3, 0->4); M = N*5 counters.
// csr word = (src*256) | (typ<<24): 24-bit byte offset, 2-bit type. hop is positional.

__global__ void k_count2(const int* __restrict__ dst, const int* __restrict__ hop,
                         int E, int* __restrict__ counts) {
    int e = blockIdx.x * blockDim.x + threadIdx.x;
    if (e < E) atomicAdd(&counts[dst[e] * 5 + (4 - hop[e])], 1);
}

__global__ __launch_bounds__(1024) void k_scan1(const int* __restrict__ in, int n,
                                                int* __restrict__ partial,
                                                int* __restrict__ blockSums) {
    __shared__ int sd[1024];
    int tid = threadIdx.x;
    int i = blockIdx.x * 1024 + tid;
    int v = (i < n) ? in[i] : 0;
    sd[tid] = v;
    __syncthreads();
    for (int off = 1; off < 1024; off <<= 1) {
        int t = (tid >= off) ? sd[tid - off] : 0;
        __syncthreads();
        sd[tid] += t;
        __syncthreads();
    }
    if (i < n) partial[i] = sd[tid];
    if (tid == 1023) blockSums[blockIdx.x] = sd[1023];
}

// single-block exclusive scan, nb <= 1024
__global__ __launch_bounds__(1024) void k_scan2big(int* __restrict__ bs, int nb) {
    __shared__ int sd[1024];
    int tid = threadIdx.x;
    int v = (tid < nb) ? bs[tid] : 0;
    sd[tid] = v;
    __syncthreads();
    for (int off = 1; off < 1024; off <<= 1) {
        int t = (tid >= off) ? sd[tid - off] : 0;
        __syncthreads();
        sd[tid] += t;
        __syncthreads();
    }
    int ex = (tid > 0) ? sd[tid - 1] : 0;
    if (tid < nb) bs[tid] = ex;
}

__global__ __launch_bounds__(1024) void k_scan3(const int* __restrict__ partial,
                                                const int* __restrict__ bs, int n,
                                                int* __restrict__ row_ptr,
                                                int* __restrict__ cursor) {
    int i = blockIdx.x * blockDim.x + threadIdx.x;
    if (i < n) {
        int v = partial[i] + bs[i >> 10];
        row_ptr[i + 1] = v;
        cursor[i + 1] = v;
    }
    if (i == 0) { row_ptr[0] = 0; cursor[0] = 0; }
}

__global__ void k_scatter2(const int* __restrict__ srcA, const int* __restrict__ dstA,
                           const int* __restrict__ typA, const int* __restrict__ hopA,
                           int E, int* __restrict__ cursor, unsigned* __restrict__ csr) {
    int e = blockIdx.x * blockDim.x + threadIdx.x;
    if (e < E) {
        int g = dstA[e] * 5 + (4 - hopA[e]);
        int p = atomicAdd(&cursor[g], 1);
        csr[p] = ((unsigned)srcA[e] << 8) | ((unsigned)typA[e] << 24);
    }
}

__global__ void k_bias(const float* __restrict__ b_edge, const float* __restrict__ b_hop,
                       float* __restrict__ bias_sums) {
    int t = blockIdx.x, d = threadIdx.x;
    float s = b_edge[d] + b_edge[DIM + d] + b_edge[2 * DIM + d];
    int base = t * (t + 1) / 2;
    for (int k = 1; k <= t + 1; ++k) s += b_hop[(base + k - 1) * DIM + d];
    bias_sums[t * DIM + d] = s;
}

// ---------------- f16 conversions ----------------

__global__ void k_convX(const float* __restrict__ in, _Float16* __restrict__ out, int n) {
    int i = (blockIdx.x * blockDim.x + threadIdx.x) * 8;
    if (i >= n) return;
    float4 a = ((const float4*)(in + i))[0];
    float4 b = ((const float4*)(in + i))[1];
    f16x8 o;
    o[0] = (_Float16)a.x; o[1] = (_Float16)a.y; o[2] = (_Float16)a.z; o[3] = (_Float16)a.w;
    o[4] = (_Float16)b.x; o[5] = (_Float16)b.y; o[6] = (_Float16)b.z; o[7] = (_Float16)b.w;
    *(f16x8*)(out + i) = o;
}

// 13 weight matrices, fp32 row-major [k][n] -> f16 transposed [n][k]
__global__ __launch_bounds__(256) void k_convW(const float* __restrict__ W_edge,
                                               const float* __restrict__ W_hop,
                                               _Float16* __restrict__ Wt) {
    int s = blockIdx.x;
    const float* src = (s < 3) ? (W_edge + (size_t)s * DIM * DIM)
                               : (W_hop + (size_t)(s - 3) * DIM * DIM);
    _Float16* dstp = Wt + (size_t)s * DIM * DIM;
    for (int it = 0; it < 64; ++it) {
        int e = it * 256 + threadIdx.x;
        int n = e >> 7, k = e & 127;
        dstp[e] = (_Float16)src[k * DIM + n];
    }
}

// -------- phase 1: hop-grouped CSR gather, 1 load per edge visit --------
// A slot map: 0..2 = edge types, 3+(k-1) = hop k

struct GatherArgs {
    const _Float16* xt;    // xh[t]   (types + hop1)
    const _Float16* xm1;   // xh[t-1] (hop2)
    const _Float16* xm2;   // xh[t-2] (hop3)
    const _Float16* xm3;   // xh[t-3] (hop4)
    _Float16* A;           // [7][N][128]
    const int* row_ptr2;   // [N*5+1] group boundaries
    const unsigned* csr;
    int t, N;
};

__global__ __launch_bounds__(256) void k_gather(GatherArgs a) {
    const int wid = threadIdx.x >> 6, lane = threadIdx.x & 63;
    const int node = blockIdx.x * 4 + wid;   // one node per wave
    if (node >= a.N) return;
    const size_t NS = (size_t)a.N * DIM;

    const int* Bp = a.row_ptr2 + node * 5;
    const int b0 = Bp[0], b1 = Bp[1], b2 = Bp[2], b3 = Bp[3], b4 = Bp[4], b5 = Bp[5];

    const char* xtl = (const char*)a.xt + lane * 4;

    float t0x = 0, t0y = 0, t1x = 0, t1y = 0, t2x = 0, t2y = 0;
    float h1x = 0, h1y = 0, h2x = 0, h2y = 0, h3x = 0, h3y = 0, h4x = 0, h4y = 0;

    // ---- loop1: all edges, type-accum; h1 segment [b3,b4) positional ----
    int e = b0;
    for (; e + 8 <= b5; e += 8) {
        unsigned mm[8];
        #pragma unroll
        for (int j = 0; j < 8; ++j) mm[j] = a.csr[e + j];
        f16x2 vv[8];
        #pragma unroll
        for (int j = 0; j < 8; ++j)
            vv[j] = *(const f16x2*)(xtl + (mm[j] & 0xFFFFFF));
        #pragma unroll
        for (int j = 0; j < 8; ++j) {
            const int typ = (int)(mm[j] >> 24);
            const float vx = (float)vv[j][0], vy = (float)vv[j][1];
            if (typ == 0)      { t0x += vx; t0y += vy; }   // wave-uniform
            else if (typ == 1) { t1x += vx; t1y += vy; }
            else               { t2x += vx; t2y += vy; }
            const int ee = e + j;
            if (ee >= b3 && ee < b4) { h1x += vx; h1y += vy; }
        }
    }
    for (; e + 4 <= b5; e += 4) {
        unsigned mm[4];
        #pragma unroll
        for (int j = 0; j < 4; ++j) mm[j] = a.csr[e + j];
        f16x2 vv[4];
        #pragma unroll
        for (int j = 0; j < 4; ++j)
            vv[j] = *(const f16x2*)(xtl + (mm[j] & 0xFFFFFF));
        #pragma unroll
        for (int j = 0; j < 4; ++j) {
            const int typ = (int)(mm[j] >> 24);
            const float vx = (float)vv[j][0], vy = (float)vv[j][1];
            if (typ == 0)      { t0x += vx; t0y += vy; }
            else if (typ == 1) { t1x += vx; t1y += vy; }
            else               { t2x += vx; t2y += vy; }
            const int ee = e + j;
            if (ee >= b3 && ee < b4) { h1x += vx; h1y += vy; }
        }
    }
    for (; e < b5; ++e) {
        const unsigned m = a.csr[e];
        const f16x2 v = *(const f16x2*)(xtl + (m & 0xFFFFFF));
        const int typ = (int)(m >> 24);
        const float vx = (float)v[0], vy = (float)v[1];
        if (typ == 0)      { t0x += vx; t0y += vy; }
        else if (typ == 1) { t1x += vx; t1y += vy; }
        else               { t2x += vx; t2y += vy; }
        if (e >= b3 && e < b4) { h1x += vx; h1y += vy; }
    }

    // ---- loop2: active hop>=2 segment [Bp[3-t], b3), buffer by position ----
    if (a.t >= 1) {
        const char* x1l = (const char*)a.xm1 + lane * 4;   // hop2: [b2,b3)
        const char* x2l = (const char*)a.xm2 + lane * 4;   // hop3: [b1,b2)
        const char* x3l = (const char*)a.xm3 + lane * 4;   // hop4: [b0,b1)
        e = Bp[3 - a.t];
        for (; e + 4 <= b3; e += 4) {
            unsigned mm[4];
            #pragma unroll
            for (int j = 0; j < 4; ++j) mm[j] = a.csr[e + j];
            f16x2 ww[4];
            #pragma unroll
            for (int j = 0; j < 4; ++j) {
                const int ee = e + j;
                const char* xb = (ee >= b2) ? x1l : (ee >= b1) ? x2l : x3l;
                ww[j] = *(const f16x2*)(xb + (mm[j] & 0xFFFFFF));
            }
            #pragma unroll
            for (int j = 0; j < 4; ++j) {
                const int ee = e + j;
                const float wx = (float)ww[j][0], wy = (float)ww[j][1];
                if (ee >= b2)      { h2x += wx; h2y += wy; }
                else if (ee >= b1) { h3x += wx; h3y += wy; }
                else               { h4x += wx; h4y += wy; }
            }
        }
        for (; e < b3; ++e) {
            const unsigned m = a.csr[e];
            const char* xb = (e >= b2) ? x1l : (e >= b1) ? x2l : x3l;
            const f16x2 w = *(const f16x2*)(xb + (m & 0xFFFFFF));
            const float wx = (float)w[0], wy = (float)w[1];
            if (e >= b2)      { h2x += wx; h2y += wy; }
            else if (e >= b1) { h3x += wx; h3y += wy; }
            else              { h4x += wx; h4y += wy; }
        }
    }

    _Float16* base = a.A + (size_t)node * DIM;
    f16x2 o;
    o[0] = (_Float16)t0x; o[1] = (_Float16)t0y; ((f16x2*)(base + 0 * NS))[lane] = o;
    o[0] = (_Float16)t1x; o[1] = (_Float16)t1y; ((f16x2*)(base + 1 * NS))[lane] = o;
    o[0] = (_Float16)t2x; o[1] = (_Float16)t2y; ((f16x2*)(base + 2 * NS))[lane] = o;
    o[0] = (_Float16)h1x; o[1] = (_Float16)h1y; ((f16x2*)(base + 3 * NS))[lane] = o;
    if (a.t >= 1) { o[0] = (_Float16)h2x; o[1] = (_Float16)h2y; ((f16x2*)(base + 4 * NS))[lane] = o; }
    if (a.t >= 2) { o[0] = (_Float16)h3x; o[1] = (_Float16)h3y; ((f16x2*)(base + 5 * NS))[lane] = o; }
    if (a.t >= 3) { o[0] = (_Float16)h4x; o[1] = (_Float16)h4y; ((f16x2*)(base + 6 * NS))[lane] = o; }
}

// -------- phase 2: C = sum_s A_s @ W_s, fused bias+relu+residual+L2norm --------
// W_s staged in LDS (XOR-swizzled store + swizzled read), A/next-W reg prefetch.

struct GemmArgs {
    const _Float16* A;     // [7][N][128]
    const _Float16* Wt;    // 13 x [n][k] f16
    const _Float16* xin;   // xh[t], residual source
    const float* bias;     // bias_sums + t*128
    float* outf;           // fp32 out (final layer) or null
    _Float16* outh;        // xh[t+1] or null
    int nsub, N;
    int wsel[7];
};

template <int NSUB>
__global__ __launch_bounds__(128, 2) void k_gemm(GemmArgs a) {
    __shared__ __align__(16) _Float16 Wlds[DIM * DIM];   // 32 KB, swizzled
    const int tid = threadIdx.x, wv = tid >> 6, lane = tid & 63;
    const int rowBase = blockIdx.x * 64 + wv * 32;
    const int lr = lane & 15, lg = lane >> 4;
    const size_t NS = (size_t)a.N * DIM;

    int r0 = rowBase + lr, r1 = rowBase + 16 + lr;
    if (r0 >= a.N) r0 = a.N - 1;
    if (r1 >= a.N) r1 = a.N - 1;

    f32x4 acc[2][8];
    #pragma unroll
    for (int rt = 0; rt < 2; ++rt)
        #pragma unroll
        for (int ct = 0; ct < 8; ++ct)
            acc[rt][ct] = (f32x4){0.f, 0.f, 0.f, 0.f};

    const int sw = (lr & 7) << 4;   // read-side XOR

    {
        const _Float16* Ws = a.Wt + (size_t)a.wsel[0] * (DIM * DIM);
        f16x8 w[16];
        #pragma unroll
        for (int i = 0; i < 16; ++i)
            w[i] = *(const f16x8*)((const char*)Ws + i * 2048 + tid * 16);
        #pragma unroll
        for (int i = 0; i < 16; ++i) {
            const int p = i * 2048 + tid * 16;
            const int q = p ^ (((p >> 8) & 7) << 4);
            *(f16x8*)((char*)Wlds + q) = w[i];
        }
    }
    f16x8 afA[2][4], afB[2][4];
    #pragma unroll
    for (int ks = 0; ks < 4; ++ks) {
        afA[0][ks] = *(const f16x8*)(a.A + (size_t)r0 * DIM + ks * 32 + lg * 8);
        afB[0][ks] = *(const f16x8*)(a.A + (size_t)r1 * DIM + ks * 32 + lg * 8);
    }
    __syncthreads();

    #pragma unroll
    for (int s = 0; s < NSUB; ++s) {
        const int cur = s & 1, nxt = cur ^ 1;
        f16x8 w[16];
        if (s + 1 < NSUB) {
            const _Float16* Wn = a.Wt + (size_t)a.wsel[s + 1] * (DIM * DIM);
            #pragma unroll
            for (int i = 0; i < 16; ++i)
                w[i] = *(const f16x8*)((const char*)Wn + i * 2048 + tid * 16);
            const _Float16* An = a.A + (size_t)(s + 1) * NS;
            #pragma unroll
            for (int ks = 0; ks < 4; ++ks) {
                afA[nxt][ks] = *(const f16x8*)(An + (size_t)r0 * DIM + ks * 32 + lg * 8);
                afB[nxt][ks] = *(const f16x8*)(An + (size_t)r1 * DIM + ks * 32 + lg * 8);
            }
        }
        #pragma unroll
        for (int ks = 0; ks < 4; ++ks) {
            const int cb = (ks * 32 + lg * 8) * 2;
            #pragma unroll
            for (int ct = 0; ct < 8; ++ct) {
                const int addr = (ct * 16 + lr) * 256 + (cb ^ sw);
                const f16x8 bf = *(const f16x8*)((const char*)Wlds + addr);
                acc[0][ct] = __builtin_amdgcn_mfma_f32_16x16x32_f16(afA[cur][ks], bf, acc[0][ct], 0, 0, 0);
                acc[1][ct] = __builtin_amdgcn_mfma_f32_16x16x32_f16(afB[cur][ks], bf, acc[1][ct], 0, 0, 0);
            }
        }
        __syncthreads();
        if (s + 1 < NSUB) {
            #pragma unroll
            for (int i = 0; i < 16; ++i) {
                const int p = i * 2048 + tid * 16;
                const int q = p ^ (((p >> 8) & 7) << 4);
                *(f16x8*)((char*)Wlds + q) = w[i];
            }
            __syncthreads();
        }
    }

    float bv[8];
    #pragma unroll
    for (int ct = 0; ct < 8; ++ct) bv[ct] = a.bias[ct * 16 + lr];

    #pragma unroll
    for (int rt = 0; rt < 2; ++rt) {
        #pragma unroll
        for (int rg = 0; rg < 4; ++rg) {
            const int row = rowBase + rt * 16 + lg * 4 + rg;
            const int rr = (row < a.N) ? row : a.N - 1;
            float v[8];
            float ss = 0.f;
            #pragma unroll
            for (int ct = 0; ct < 8; ++ct) {
                const float xval = (float)a.xin[(size_t)rr * DIM + ct * 16 + lr];
                const float tv = fmaxf(acc[rt][ct][rg] + bv[ct], 0.f) + xval;
                v[ct] = tv;
                ss += tv * tv;
            }
            ss += __shfl_xor(ss, 1, 64);
            ss += __shfl_xor(ss, 2, 64);
            ss += __shfl_xor(ss, 4, 64);
            ss += __shfl_xor(ss, 8, 64);
            const float inv = 1.f / fmaxf(sqrtf(ss), 1e-12f);
            if (row < a.N) {
                #pragma unroll
                for (int ct = 0; ct < 8; ++ct) {
                    const int col = ct * 16 + lr;
                    const float ov = v[ct] * inv;
                    if (a.outf) a.outf[(size_t)row * DIM + col] = ov;
                    if (a.outh) a.outh[(size_t)row * DIM + col] = (_Float16)ov;
                }
            }
        }
    }
}

// ---------------- launch ----------------

static inline size_t align_up(size_t v, size_t a) { return (v + a - 1) & ~(a - 1); }

extern "C" void kernel_launch(void* const* d_in, const int* in_sizes, int n_in,
                              void* d_out, int out_size, void* d_ws, size_t ws_size,
                              hipStream_t stream) {
    const float* x        = (const float*)d_in[0];
    const int* edge_index = (const int*)d_in[1];
    const int* edge_hop   = (const int*)d_in[2];
    const int* edge_type  = (const int*)d_in[3];
    const float* W_edge   = (const float*)d_in[4];
    const float* b_edge   = (const float*)d_in[5];
    const float* W_hop    = (const float*)d_in[6];
    const float* b_hop    = (const float*)d_in[7];
    float* out = (float*)d_out;

    int N = in_sizes[0] / DIM;   // 50000
    int E = in_sizes[2];         // 600000
    const int* srcA = edge_index;
    const int* dstA = edge_index + E;
    const int M = N * 5;         // grouped counters

    size_t NSh = (size_t)N * DIM * sizeof(_Float16);
    size_t off = 0;
    char* wsb = (char*)d_ws;
    _Float16* xh0     = (_Float16*)(wsb + off);  off = align_up(off + NSh, 64);
    _Float16* xh1     = (_Float16*)(wsb + off);  off = align_up(off + NSh, 64);
    _Float16* xh2     = (_Float16*)(wsb + off);  off = align_up(off + NSh, 64);
    _Float16* xh3     = (_Float16*)(wsb + off);  off = align_up(off + NSh, 64);
    _Float16* A       = (_Float16*)(wsb + off);  off = align_up(off + 7 * NSh, 64);
    _Float16* Wt      = (_Float16*)(wsb + off);  off = align_up(off + 13 * DIM * DIM * sizeof(_Float16), 64);
    int* counts2      = (int*)(wsb + off);       off = align_up(off + (size_t)M * 4, 64);
    int* partial2     = (int*)(wsb + off);       off = align_up(off + (size_t)M * 4, 64);
    int* blockSums    = (int*)(wsb + off);       off = align_up(off + 1024 * 4, 64);
    int* row_ptr2     = (int*)(wsb + off);       off = align_up(off + (size_t)(M + 1) * 4, 64);
    int* cursor2      = (int*)(wsb + off);       off = align_up(off + (size_t)(M + 1) * 4, 64);
    unsigned* csr     = (unsigned*)(wsb + off);  off = align_up(off + (size_t)E * 4, 64);
    float* bias_sums  = (float*)(wsb + off);     off = align_up(off + 4 * DIM * 4, 64);
    (void)ws_size;  // ~150 MB

    // CSR build (grouped by (dst, hop desc))
    hipMemsetAsync(counts2, 0, (size_t)M * 4, stream);
    k_count2<<<(E + 255) / 256, 256, 0, stream>>>(dstA, edge_hop, E, counts2);
    int nb = (M + 1023) / 1024;   // 245
    k_scan1<<<nb, 1024, 0, stream>>>(counts2, M, partial2, blockSums);
    k_scan2big<<<1, 1024, 0, stream>>>(blockSums, nb);
    k_scan3<<<nb, 1024, 0, stream>>>(partial2, blockSums, M, row_ptr2, cursor2);
    k_scatter2<<<(E + 255) / 256, 256, 0, stream>>>(srcA, dstA, edge_type, edge_hop, E, cursor2, csr);
    k_bias<<<4, DIM, 0, stream>>>(b_edge, b_hop, bias_sums);

    // f16 conversions
    k_convX<<<(N * DIM / 8 + 255) / 256, 256, 0, stream>>>(x, xh0, N * DIM);
    k_convW<<<13, 256, 0, stream>>>(W_edge, W_hop, Wt);

    _Float16* xh_ptr[4] = { xh0, xh1, xh2, xh3 };

    for (int t = 0; t < NLAYER; ++t) {
        GatherArgs g;
        g.xt  = xh_ptr[t];
        g.xm1 = (t >= 1) ? xh_ptr[t - 1] : xh0;
        g.xm2 = (t >= 2) ? xh_ptr[t - 2] : xh0;
        g.xm3 = (t >= 3) ? xh_ptr[t - 3] : xh0;
        g.A = A; g.row_ptr2 = row_ptr2; g.csr = csr; g.t = t; g.N = N;
        k_gather<<<(N + 3) / 4, 256, 0, stream>>>(g);

        GemmArgs m;
        m.A = A; m.Wt = Wt; m.xin = xh_ptr[t];
        m.bias = bias_sums + t * DIM;
        m.outf = (t == 3) ? out : nullptr;
        m.outh = (t < 3) ? xh_ptr[t + 1] : nullptr;
        m.nsub = t + 4; m.N = N;
        int base = t * (t + 1) / 2;
        for (int s = 0; s < 3; ++s) m.wsel[s] = s;
        for (int j = 0; j <= t; ++j) m.wsel[3 + j] = 3 + base + j;
        for (int s = m.nsub; s < 7; ++s) m.wsel[s] = 0;

        const int gb = (N + 63) / 64;
        switch (m.nsub) {
            case 4: k_gemm<4><<<gb, 128, 0, stream>>>(m); break;
            case 5: k_gemm<5><<<gb, 128, 0, stream>>>(m); break;
            case 6: k_gemm<6><<<gb, 128, 0, stream>>>(m); break;
            default: k_gemm<7><<<gb, 128, 0, stream>>>(m); break;
        }
    }
}

// Round 9
// 352.988 us; speedup vs baseline: 1.8983x; 1.1017x over previous
//
#include <hip/hip_runtime.h>
#include <hip/hip_bf16.h>

#define DIM 128
#define NLAYER 4

typedef _Float16 f16x8 __attribute__((ext_vector_type(8)));
typedef _Float16 f16x2 __attribute__((ext_vector_type(2)));
typedef float f32x4 __attribute__((ext_vector_type(4)));

// ---------------- CSR build (dst-sorted; word = src<<8 | typ<<24 | hop<<26) ----

__global__ void k_count(const int* __restrict__ dst, int E, int* __restrict__ counts) {
    int e = blockIdx.x * blockDim.x + threadIdx.x;
    if (e < E) atomicAdd(&counts[dst[e]], 1);
}

__global__ __launch_bounds__(1024) void k_scan1(const int* __restrict__ in, int n,
                                                int* __restrict__ partial,
                                                int* __restrict__ blockSums) {
    __shared__ int sd[1024];
    int tid = threadIdx.x;
    int i = blockIdx.x * 1024 + tid;
    int v = (i < n) ? in[i] : 0;
    sd[tid] = v;
    __syncthreads();
    for (int off = 1; off < 1024; off <<= 1) {
        int t = (tid >= off) ? sd[tid - off] : 0;
        __syncthreads();
        sd[tid] += t;
        __syncthreads();
    }
    if (i < n) partial[i] = sd[tid];
    if (tid == 1023) blockSums[blockIdx.x] = sd[1023];
}

__global__ void k_scan2(int* __restrict__ bs, int nb) {   // nb <= 64
    int lane = threadIdx.x;
    int v = (lane < nb) ? bs[lane] : 0;
    for (int off = 1; off < 64; off <<= 1) {
        int t = __shfl_up(v, off, 64);
        if (lane >= off) v += t;
    }
    int ex = __shfl_up(v, 1, 64);
    if (lane == 0) ex = 0;
    if (lane < nb) bs[lane] = ex;
}

__global__ __launch_bounds__(1024) void k_scan3(const int* __restrict__ partial,
                                                const int* __restrict__ bs, int n,
                                                int* __restrict__ row_ptr,
                                                int* __restrict__ cursor) {
    int i = blockIdx.x * blockDim.x + threadIdx.x;
    if (i < n) {
        int v = partial[i] + bs[i >> 10];
        row_ptr[i + 1] = v;
        cursor[i + 1] = v;
    }
    if (i == 0) { row_ptr[0] = 0; cursor[0] = 0; }
}

__global__ void k_scatter(const int* __restrict__ srcA, const int* __restrict__ dstA,
                          const int* __restrict__ typA, const int* __restrict__ hopA,
                          int E, int* __restrict__ cursor, unsigned* __restrict__ csr) {
    int e = blockIdx.x * blockDim.x + threadIdx.x;
    if (e < E) {
        int d = dstA[e];
        int p = atomicAdd(&cursor[d], 1);
        csr[p] = ((unsigned)srcA[e] << 8) | ((unsigned)typA[e] << 24)
               | ((unsigned)hopA[e] << 26);
    }
}

__global__ void k_bias(const float* __restrict__ b_edge, const float* __restrict__ b_hop,
                       float* __restrict__ bias_sums) {
    int t = blockIdx.x, d = threadIdx.x;
    float s = b_edge[d] + b_edge[DIM + d] + b_edge[2 * DIM + d];
    int base = t * (t + 1) / 2;
    for (int k = 1; k <= t + 1; ++k) s += b_hop[(base + k - 1) * DIM + d];
    bias_sums[t * DIM + d] = s;
}

// ---------------- f16 conversions ----------------

__global__ void k_convX(const float* __restrict__ in, _Float16* __restrict__ out, int n) {
    int i = (blockIdx.x * blockDim.x + threadIdx.x) * 8;
    if (i >= n) return;
    float4 a = ((const float4*)(in + i))[0];
    float4 b = ((const float4*)(in + i))[1];
    f16x8 o;
    o[0] = (_Float16)a.x; o[1] = (_Float16)a.y; o[2] = (_Float16)a.z; o[3] = (_Float16)a.w;
    o[4] = (_Float16)b.x; o[5] = (_Float16)b.y; o[6] = (_Float16)b.z; o[7] = (_Float16)b.w;
    *(f16x8*)(out + i) = o;
}

// 13 weight matrices, fp32 row-major [k][n] -> f16 transposed [n][k]
__global__ __launch_bounds__(256) void k_convW(const float* __restrict__ W_edge,
                                               const float* __restrict__ W_hop,
                                               _Float16* __restrict__ Wt) {
    int s = blockIdx.x;
    const float* src = (s < 3) ? (W_edge + (size_t)s * DIM * DIM)
                               : (W_hop + (size_t)(s - 3) * DIM * DIM);
    _Float16* dstp = Wt + (size_t)s * DIM * DIM;
    for (int it = 0; it < 64; ++it) {
        int e = it * 256 + threadIdx.x;
        int n = e >> 7, k = e & 127;
        dstp[e] = (_Float16)src[k * DIM + n];
    }
}

// -------- phase 1: single-pass gather; future hop slots accumulated now --------
// At layer TAU, the loaded row xh[TAU][src] serves: its type slot (this layer),
// hop-1 (this layer), and hop-k>=2 slots of layer TAU+k-1 (written ahead).
// Ahop slot index for (layer t', hop k) = t'(t'+1)/2 + (k-1).

struct GatherArgs {
    const _Float16* xt;    // xh[TAU]
    _Float16* Atype;       // [3][N][128], reused every layer
    _Float16* Ahop;        // [10][N][128], triangular schedule
    const int* row_ptr;
    const unsigned* csr;
    int N;
};

template <int TAU>
__global__ __launch_bounds__(256) void k_gather(GatherArgs a) {
    const int wid = threadIdx.x >> 6, lane = threadIdx.x & 63;
    const int node = blockIdx.x * 4 + wid;   // one node per wave
    if (node >= a.N) return;
    const size_t NS = (size_t)a.N * DIM;

    const char* xtl = (const char*)a.xt + lane * 4;

    float t0x = 0, t0y = 0, t1x = 0, t1y = 0, t2x = 0, t2y = 0;
    float h1x = 0, h1y = 0, h2x = 0, h2y = 0, h3x = 0, h3y = 0, h4x = 0, h4y = 0;

    const int e0 = a.row_ptr[node], e1 = a.row_ptr[node + 1];
    int e = e0;

    #define ACCUM(m, v)                                                        \
        {                                                                      \
            const int typ = (int)((m) >> 24) & 3;                              \
            const int hop = (int)((m) >> 26);                                  \
            const float vx = (float)(v)[0], vy = (float)(v)[1];                \
            if (typ == 0)      { t0x += vx; t0y += vy; }                       \
            else if (typ == 1) { t1x += vx; t1y += vy; }                       \
            else               { t2x += vx; t2y += vy; }                       \
            if (hop == 1)                    { h1x += vx; h1y += vy; }         \
            else if (TAU <= 2 && hop == 2)   { h2x += vx; h2y += vy; }         \
            else if (TAU <= 1 && hop == 3)   { h3x += vx; h3y += vy; }         \
            else if (TAU == 0 && hop == 4)   { h4x += vx; h4y += vy; }         \
        }

    for (; e + 8 <= e1; e += 8) {
        unsigned mm[8];
        #pragma unroll
        for (int j = 0; j < 8; ++j) mm[j] = a.csr[e + j];
        f16x2 vv[8];
        #pragma unroll
        for (int j = 0; j < 8; ++j)
            vv[j] = *(const f16x2*)(xtl + (mm[j] & 0xFFFFFF));
        #pragma unroll
        for (int j = 0; j < 8; ++j) ACCUM(mm[j], vv[j])
    }
    for (; e + 4 <= e1; e += 4) {
        unsigned mm[4];
        #pragma unroll
        for (int j = 0; j < 4; ++j) mm[j] = a.csr[e + j];
        f16x2 vv[4];
        #pragma unroll
        for (int j = 0; j < 4; ++j)
            vv[j] = *(const f16x2*)(xtl + (mm[j] & 0xFFFFFF));
        #pragma unroll
        for (int j = 0; j < 4; ++j) ACCUM(mm[j], vv[j])
    }
    for (; e < e1; ++e) {
        const unsigned m = a.csr[e];
        const f16x2 v = *(const f16x2*)(xtl + (m & 0xFFFFFF));
        ACCUM(m, v)
    }
    #undef ACCUM

    // writes: 3 type slots (this layer) + h1 (this layer) + future hop slots
    _Float16* tb = a.Atype + (size_t)node * DIM;
    f16x2 o;
    o[0] = (_Float16)t0x; o[1] = (_Float16)t0y; ((f16x2*)(tb + 0 * NS))[lane] = o;
    o[0] = (_Float16)t1x; o[1] = (_Float16)t1y; ((f16x2*)(tb + 1 * NS))[lane] = o;
    o[0] = (_Float16)t2x; o[1] = (_Float16)t2y; ((f16x2*)(tb + 2 * NS))[lane] = o;

    _Float16* hb = a.Ahop + (size_t)node * DIM;
    // idx(t',k) = t'(t'+1)/2 + k-1 ; at layer TAU: h_k -> idx(TAU+k-1, k)
    constexpr int i1 = (TAU * (TAU + 1)) / 2;                         // h1
    o[0] = (_Float16)h1x; o[1] = (_Float16)h1y; ((f16x2*)(hb + (size_t)i1 * NS))[lane] = o;
    if (TAU <= 2) {
        constexpr int tp = TAU + 1;
        constexpr int i2 = (tp * (tp + 1)) / 2 + 1;
        o[0] = (_Float16)h2x; o[1] = (_Float16)h2y; ((f16x2*)(hb + (size_t)i2 * NS))[lane] = o;
    }
    if (TAU <= 1) {
        constexpr int tp = TAU + 2;
        constexpr int i3 = (tp * (tp + 1)) / 2 + 2;
        o[0] = (_Float16)h3x; o[1] = (_Float16)h3y; ((f16x2*)(hb + (size_t)i3 * NS))[lane] = o;
    }
    if (TAU == 0) {
        constexpr int i4 = (3 * 4) / 2 + 3;   // layer 3, hop 4 -> 9
        o[0] = (_Float16)h4x; o[1] = (_Float16)h4y; ((f16x2*)(hb + (size_t)i4 * NS))[lane] = o;
    }
}

// -------- phase 2: C = sum_s A_s @ W_s, fused bias+relu+residual+L2norm --------
// W_s staged in LDS (XOR-swizzled store + swizzled read), A/next-W reg prefetch.

struct GemmArgs {
    const _Float16* Aslot[7];   // per-sublayer A base pointers
    const _Float16* Wt;         // 13 x [n][k] f16
    const _Float16* xin;        // xh[t], residual source
    const float* bias;          // bias_sums + t*128
    float* outf;                // fp32 out (final layer) or null
    _Float16* outh;             // xh[t+1] or null
    int N;
    int wsel[7];
};

template <int NSUB>
__global__ __launch_bounds__(128, 2) void k_gemm(GemmArgs a) {
    __shared__ __align__(16) _Float16 Wlds[DIM * DIM];   // 32 KB, swizzled
    const int tid = threadIdx.x, wv = tid >> 6, lane = tid & 63;
    const int rowBase = blockIdx.x * 64 + wv * 32;
    const int lr = lane & 15, lg = lane >> 4;

    int r0 = rowBase + lr, r1 = rowBase + 16 + lr;
    if (r0 >= a.N) r0 = a.N - 1;
    if (r1 >= a.N) r1 = a.N - 1;

    f32x4 acc[2][8];
    #pragma unroll
    for (int rt = 0; rt < 2; ++rt)
        #pragma unroll
        for (int ct = 0; ct < 8; ++ct)
            acc[rt][ct] = (f32x4){0.f, 0.f, 0.f, 0.f};

    const int sw = (lr & 7) << 4;   // read-side XOR

    {
        const _Float16* Ws = a.Wt + (size_t)a.wsel[0] * (DIM * DIM);
        f16x8 w[16];
        #pragma unroll
        for (int i = 0; i < 16; ++i)
            w[i] = *(const f16x8*)((const char*)Ws + i * 2048 + tid * 16);
        #pragma unroll
        for (int i = 0; i < 16; ++i) {
            const int p = i * 2048 + tid * 16;
            const int q = p ^ (((p >> 8) & 7) << 4);
            *(f16x8*)((char*)Wlds + q) = w[i];
        }
    }
    f16x8 afA[2][4], afB[2][4];
    #pragma unroll
    for (int ks = 0; ks < 4; ++ks) {
        afA[0][ks] = *(const f16x8*)(a.Aslot[0] + (size_t)r0 * DIM + ks * 32 + lg * 8);
        afB[0][ks] = *(const f16x8*)(a.Aslot[0] + (size_t)r1 * DIM + ks * 32 + lg * 8);
    }
    __syncthreads();

    #pragma unroll
    for (int s = 0; s < NSUB; ++s) {
        const int cur = s & 1, nxt = cur ^ 1;
        f16x8 w[16];
        if (s + 1 < NSUB) {
            const _Float16* Wn = a.Wt + (size_t)a.wsel[s + 1] * (DIM * DIM);
            #pragma unroll
            for (int i = 0; i < 16; ++i)
                w[i] = *(const f16x8*)((const char*)Wn + i * 2048 + tid * 16);
            const _Float16* An = a.Aslot[s + 1];
            #pragma unroll
            for (int ks = 0; ks < 4; ++ks) {
                afA[nxt][ks] = *(const f16x8*)(An + (size_t)r0 * DIM + ks * 32 + lg * 8);
                afB[nxt][ks] = *(const f16x8*)(An + (size_t)r1 * DIM + ks * 32 + lg * 8);
            }
        }
        #pragma unroll
        for (int ks = 0; ks < 4; ++ks) {
            const int cb = (ks * 32 + lg * 8) * 2;
            #pragma unroll
            for (int ct = 0; ct < 8; ++ct) {
                const int addr = (ct * 16 + lr) * 256 + (cb ^ sw);
                const f16x8 bf = *(const f16x8*)((const char*)Wlds + addr);
                acc[0][ct] = __builtin_amdgcn_mfma_f32_16x16x32_f16(afA[cur][ks], bf, acc[0][ct], 0, 0, 0);
                acc[1][ct] = __builtin_amdgcn_mfma_f32_16x16x32_f16(afB[cur][ks], bf, acc[1][ct], 0, 0, 0);
            }
        }
        __syncthreads();
        if (s + 1 < NSUB) {
            #pragma unroll
            for (int i = 0; i < 16; ++i) {
                const int p = i * 2048 + tid * 16;
                const int q = p ^ (((p >> 8) & 7) << 4);
                *(f16x8*)((char*)Wlds + q) = w[i];
            }
            __syncthreads();
        }
    }

    float bv[8];
    #pragma unroll
    for (int ct = 0; ct < 8; ++ct) bv[ct] = a.bias[ct * 16 + lr];

    #pragma unroll
    for (int rt = 0; rt < 2; ++rt) {
        #pragma unroll
        for (int rg = 0; rg < 4; ++rg) {
            const int row = rowBase + rt * 16 + lg * 4 + rg;
            const int rr = (row < a.N) ? row : a.N - 1;
            float v[8];
            float ss = 0.f;
            #pragma unroll
            for (int ct = 0; ct < 8; ++ct) {
                const float xval = (float)a.xin[(size_t)rr * DIM + ct * 16 + lr];
                const float tv = fmaxf(acc[rt][ct][rg] + bv[ct], 0.f) + xval;
                v[ct] = tv;
                ss += tv * tv;
            }
            ss += __shfl_xor(ss, 1, 64);
            ss += __shfl_xor(ss, 2, 64);
            ss += __shfl_xor(ss, 4, 64);
            ss += __shfl_xor(ss, 8, 64);
            const float inv = 1.f / fmaxf(sqrtf(ss), 1e-12f);
            if (row < a.N) {
                #pragma unroll
                for (int ct = 0; ct < 8; ++ct) {
                    const int col = ct * 16 + lr;
                    const float ov = v[ct] * inv;
                    if (a.outf) a.outf[(size_t)row * DIM + col] = ov;
                    if (a.outh) a.outh[(size_t)row * DIM + col] = (_Float16)ov;
                }
            }
        }
    }
}

// ---------------- launch ----------------

static inline size_t align_up(size_t v, size_t a) { return (v + a - 1) & ~(a - 1); }

extern "C" void kernel_launch(void* const* d_in, const int* in_sizes, int n_in,
                              void* d_out, int out_size, void* d_ws, size_t ws_size,
                              hipStream_t stream) {
    const float* x        = (const float*)d_in[0];
    const int* edge_index = (const int*)d_in[1];
    const int* edge_hop   = (const int*)d_in[2];
    const int* edge_type  = (const int*)d_in[3];
    const float* W_edge   = (const float*)d_in[4];
    const float* b_edge   = (const float*)d_in[5];
    const float* W_hop    = (const float*)d_in[6];
    const float* b_hop    = (const float*)d_in[7];
    float* out = (float*)d_out;

    int N = in_sizes[0] / DIM;   // 50000
    int E = in_sizes[2];         // 600000
    const int* srcA = edge_index;
    const int* dstA = edge_index + E;

    size_t NSh = (size_t)N * DIM * sizeof(_Float16);
    size_t off = 0;
    char* wsb = (char*)d_ws;
    _Float16* xh0     = (_Float16*)(wsb + off);  off = align_up(off + NSh, 64);
    _Float16* xh1     = (_Float16*)(wsb + off);  off = align_up(off + NSh, 64);
    _Float16* xh2     = (_Float16*)(wsb + off);  off = align_up(off + NSh, 64);
    _Float16* xh3     = (_Float16*)(wsb + off);  off = align_up(off + NSh, 64);
    _Float16* Atype   = (_Float16*)(wsb + off);  off = align_up(off + 3 * NSh, 64);
    _Float16* Ahop    = (_Float16*)(wsb + off);  off = align_up(off + 10 * NSh, 64);
    _Float16* Wt      = (_Float16*)(wsb + off);  off = align_up(off + 13 * DIM * DIM * sizeof(_Float16), 64);
    int* counts       = (int*)(wsb + off);       off = align_up(off + (size_t)N * 4, 64);
    int* partial      = (int*)(wsb + off);       off = align_up(off + (size_t)N * 4, 64);
    int* blockSums    = (int*)(wsb + off);       off = align_up(off + 64 * 4, 64);
    int* row_ptr      = (int*)(wsb + off);       off = align_up(off + (size_t)(N + 1) * 4, 64);
    int* cursor       = (int*)(wsb + off);       off = align_up(off + (size_t)(N + 1) * 4, 64);
    unsigned* csr     = (unsigned*)(wsb + off);  off = align_up(off + (size_t)E * 4, 64);
    float* bias_sums  = (float*)(wsb + off);     off = align_up(off + 4 * DIM * 4, 64);
    (void)ws_size;  // ~225 MB

    // CSR build
    hipMemsetAsync(counts, 0, (size_t)N * 4, stream);
    k_count<<<(E + 255) / 256, 256, 0, stream>>>(dstA, E, counts);
    int nb = (N + 1023) / 1024;   // 49
    k_scan1<<<nb, 1024, 0, stream>>>(counts, N, partial, blockSums);
    k_scan2<<<1, 64, 0, stream>>>(blockSums, nb);
    k_scan3<<<nb, 1024, 0, stream>>>(partial, blockSums, N, row_ptr, cursor);
    k_scatter<<<(E + 255) / 256, 256, 0, stream>>>(srcA, dstA, edge_type, edge_hop, E, cursor, csr);
    k_bias<<<4, DIM, 0, stream>>>(b_edge, b_hop, bias_sums);

    // f16 conversions
    k_convX<<<(N * DIM / 8 + 255) / 256, 256, 0, stream>>>(x, xh0, N * DIM);
    k_convW<<<13, 256, 0, stream>>>(W_edge, W_hop, Wt);

    _Float16* xh_ptr[4] = { xh0, xh1, xh2, xh3 };
    const size_t NS = (size_t)N * DIM;

    for (int t = 0; t < NLAYER; ++t) {
        GatherArgs g;
        g.xt = xh_ptr[t];
        g.Atype = Atype; g.Ahop = Ahop;
        g.row_ptr = row_ptr; g.csr = csr; g.N = N;
        const int gbg = (N + 3) / 4;
        switch (t) {
            case 0: k_gather<0><<<gbg, 256, 0, stream>>>(g); break;
            case 1: k_gather<1><<<gbg, 256, 0, stream>>>(g); break;
            case 2: k_gather<2><<<gbg, 256, 0, stream>>>(g); break;
            default: k_gather<3><<<gbg, 256, 0, stream>>>(g); break;
        }

        GemmArgs m;
        m.Wt = Wt; m.xin = xh_ptr[t];
        m.bias = bias_sums + t * DIM;
        m.outf = (t == 3) ? out : nullptr;
        m.outh = (t < 3) ? xh_ptr[t + 1] : nullptr;
        m.N = N;
        const int nsub = t + 4;
        const int base = t * (t + 1) / 2;
        for (int s = 0; s < 3; ++s) { m.wsel[s] = s; m.Aslot[s] = Atype + (size_t)s * NS; }
        for (int j = 0; j <= t; ++j) {
            m.wsel[3 + j] = 3 + base + j;
            m.Aslot[3 + j] = Ahop + (size_t)(base + j) * NS;
        }
        for (int s = nsub; s < 7; ++s) { m.wsel[s] = 0; m.Aslot[s] = Atype; }

        const int gb = (N + 63) / 64;
        switch (nsub) {
            case 4: k_gemm<4><<<gb, 128, 0, stream>>>(m); break;
            case 5: k_gemm<5><<<gb, 128, 0, stream>>>(m); break;
            case 6: k_gemm<6><<<gb, 128, 0, stream>>>(m); break;
            default: k_gemm<7><<<gb, 128, 0, stream>>>(m); break;
        }
    }
}

// Round 10
// 343.630 us; speedup vs baseline: 1.9500x; 1.0272x over previous
//
#include <hip/hip_runtime.h>
#include <hip/hip_bf16.h>

#define DIM 128
#define NLAYER 4

typedef _Float16 f16x8 __attribute__((ext_vector_type(8)));
typedef _Float16 f16x2 __attribute__((ext_vector_type(2)));
typedef float f32x4 __attribute__((ext_vector_type(4)));

// Physical slot map for the 10 logical hop slots (ring allocation, peak live = 6).
// idx(t',k) = t'(t'+1)/2 + (k-1). Collision-checked: lifetimes disjoint per phys slot.
static constexpr int PHYS[10] = {0, 4, 1, 0, 5, 2, 1, 4, 6, 3};

// ---------------- CSR build (dst-sorted; word = src<<8 | typ<<24 | hop<<26) ----

__global__ void k_count(const int* __restrict__ dst, int E, int* __restrict__ counts) {
    int e = blockIdx.x * blockDim.x + threadIdx.x;
    if (e < E) atomicAdd(&counts[dst[e]], 1);
}

__global__ __launch_bounds__(1024) void k_scan1(const int* __restrict__ in, int n,
                                                int* __restrict__ partial,
                                                int* __restrict__ blockSums) {
    __shared__ int sd[1024];
    int tid = threadIdx.x;
    int i = blockIdx.x * 1024 + tid;
    int v = (i < n) ? in[i] : 0;
    sd[tid] = v;
    __syncthreads();
    for (int off = 1; off < 1024; off <<= 1) {
        int t = (tid >= off) ? sd[tid - off] : 0;
        __syncthreads();
        sd[tid] += t;
        __syncthreads();
    }
    if (i < n) partial[i] = sd[tid];
    if (tid == 1023) blockSums[blockIdx.x] = sd[1023];
}

__global__ void k_scan2(int* __restrict__ bs, int nb) {   // nb <= 64
    int lane = threadIdx.x;
    int v = (lane < nb) ? bs[lane] : 0;
    for (int off = 1; off < 64; off <<= 1) {
        int t = __shfl_up(v, off, 64);
        if (lane >= off) v += t;
    }
    int ex = __shfl_up(v, 1, 64);
    if (lane == 0) ex = 0;
    if (lane < nb) bs[lane] = ex;
}

__global__ __launch_bounds__(1024) void k_scan3(const int* __restrict__ partial,
                                                const int* __restrict__ bs, int n,
                                                int* __restrict__ row_ptr,
                                                int* __restrict__ cursor) {
    int i = blockIdx.x * blockDim.x + threadIdx.x;
    if (i < n) {
        int v = partial[i] + bs[i >> 10];
        row_ptr[i + 1] = v;
        cursor[i + 1] = v;
    }
    if (i == 0) { row_ptr[0] = 0; cursor[0] = 0; }
}

__global__ void k_scatter(const int* __restrict__ srcA, const int* __restrict__ dstA,
                          const int* __restrict__ typA, const int* __restrict__ hopA,
                          int E, int* __restrict__ cursor, unsigned* __restrict__ csr) {
    int e = blockIdx.x * blockDim.x + threadIdx.x;
    if (e < E) {
        int d = dstA[e];
        int p = atomicAdd(&cursor[d], 1);
        csr[p] = ((unsigned)srcA[e] << 8) | ((unsigned)typA[e] << 24)
               | ((unsigned)hopA[e] << 26);
    }
}

__global__ void k_bias(const float* __restrict__ b_edge, const float* __restrict__ b_hop,
                       float* __restrict__ bias_sums) {
    int t = blockIdx.x, d = threadIdx.x;
    float s = b_edge[d] + b_edge[DIM + d] + b_edge[2 * DIM + d];
    int base = t * (t + 1) / 2;
    for (int k = 1; k <= t + 1; ++k) s += b_hop[(base + k - 1) * DIM + d];
    bias_sums[t * DIM + d] = s;
}

// ---------------- f16 conversions ----------------

__global__ void k_convX(const float* __restrict__ in, _Float16* __restrict__ out, int n) {
    int i = (blockIdx.x * blockDim.x + threadIdx.x) * 8;
    if (i >= n) return;
    float4 a = ((const float4*)(in + i))[0];
    float4 b = ((const float4*)(in + i))[1];
    f16x8 o;
    o[0] = (_Float16)a.x; o[1] = (_Float16)a.y; o[2] = (_Float16)a.z; o[3] = (_Float16)a.w;
    o[4] = (_Float16)b.x; o[5] = (_Float16)b.y; o[6] = (_Float16)b.z; o[7] = (_Float16)b.w;
    *(f16x8*)(out + i) = o;
}

// 13 weight matrices, fp32 row-major [k][n] -> f16 transposed [n][k]
__global__ __launch_bounds__(256) void k_convW(const float* __restrict__ W_edge,
                                               const float* __restrict__ W_hop,
                                               _Float16* __restrict__ Wt) {
    int s = blockIdx.x;
    const float* src = (s < 3) ? (W_edge + (size_t)s * DIM * DIM)
                               : (W_hop + (size_t)(s - 3) * DIM * DIM);
    _Float16* dstp = Wt + (size_t)s * DIM * DIM;
    for (int it = 0; it < 64; ++it) {
        int e = it * 256 + threadIdx.x;
        int n = e >> 7, k = e & 127;
        dstp[e] = (_Float16)src[k * DIM + n];
    }
}

// -------- phase 1: single-pass gather; future hop slots accumulated now --------
// 64-thread blocks: node = blockIdx.x is provably wave-uniform, so csr words,
// typ/hop and branches scalarize (s_load + s_cmp + uniform branch), and the
// gather address is SGPR-base + constant lane offset.

struct GatherArgs {
    const _Float16* __restrict__ xt;    // xh[TAU]
    _Float16* __restrict__ Atype;       // [3][N][128], reused every layer
    _Float16* __restrict__ Ahop;        // [7][N][128] physical ring slots
    const int* __restrict__ row_ptr;
    const unsigned* __restrict__ csr;
    int N;
};

template <int TAU>
__global__ __launch_bounds__(64) void k_gather(GatherArgs a) {
    const int node = blockIdx.x;            // wave-uniform
    const int lane = threadIdx.x;
    const size_t NS = (size_t)a.N * DIM;

    const char* xtl = (const char*)a.xt + lane * 4;

    float t0x = 0, t0y = 0, t1x = 0, t1y = 0, t2x = 0, t2y = 0;
    float h1x = 0, h1y = 0, h2x = 0, h2y = 0, h3x = 0, h3y = 0, h4x = 0, h4y = 0;

    const int e0 = a.row_ptr[node], e1 = a.row_ptr[node + 1];
    int e = e0;

    #define ACCUM(m, v)                                                        \
        {                                                                      \
            const int typ = (int)((m) >> 24) & 3;                              \
            const int hop = (int)((m) >> 26);                                  \
            const float vx = (float)(v)[0], vy = (float)(v)[1];                \
            if (typ == 0)      { t0x += vx; t0y += vy; }                       \
            else if (typ == 1) { t1x += vx; t1y += vy; }                       \
            else               { t2x += vx; t2y += vy; }                       \
            if (hop == 1)                    { h1x += vx; h1y += vy; }         \
            else if (TAU <= 2 && hop == 2)   { h2x += vx; h2y += vy; }         \
            else if (TAU <= 1 && hop == 3)   { h3x += vx; h3y += vy; }         \
            else if (TAU == 0 && hop == 4)   { h4x += vx; h4y += vy; }         \
        }

    for (; e + 8 <= e1; e += 8) {
        unsigned mm[8];
        #pragma unroll
        for (int j = 0; j < 8; ++j) mm[j] = a.csr[e + j];
        f16x2 vv[8];
        #pragma unroll
        for (int j = 0; j < 8; ++j)
            vv[j] = *(const f16x2*)(xtl + (mm[j] & 0xFFFFFF));
        #pragma unroll
        for (int j = 0; j < 8; ++j) ACCUM(mm[j], vv[j])
    }
    for (; e + 4 <= e1; e += 4) {
        unsigned mm[4];
        #pragma unroll
        for (int j = 0; j < 4; ++j) mm[j] = a.csr[e + j];
        f16x2 vv[4];
        #pragma unroll
        for (int j = 0; j < 4; ++j)
            vv[j] = *(const f16x2*)(xtl + (mm[j] & 0xFFFFFF));
        #pragma unroll
        for (int j = 0; j < 4; ++j) ACCUM(mm[j], vv[j])
    }
    for (; e < e1; ++e) {
        const unsigned m = a.csr[e];
        const f16x2 v = *(const f16x2*)(xtl + (m & 0xFFFFFF));
        ACCUM(m, v)
    }
    #undef ACCUM

    _Float16* tb = a.Atype + (size_t)node * DIM;
    f16x2 o;
    o[0] = (_Float16)t0x; o[1] = (_Float16)t0y; ((f16x2*)(tb + 0 * NS))[lane] = o;
    o[0] = (_Float16)t1x; o[1] = (_Float16)t1y; ((f16x2*)(tb + 1 * NS))[lane] = o;
    o[0] = (_Float16)t2x; o[1] = (_Float16)t2y; ((f16x2*)(tb + 2 * NS))[lane] = o;

    _Float16* hb = a.Ahop + (size_t)node * DIM;
    // at layer TAU: h_k -> logical idx(TAU+k-1, k) -> PHYS ring slot
    {
        constexpr int P1 = PHYS[(TAU * (TAU + 1)) / 2];
        o[0] = (_Float16)h1x; o[1] = (_Float16)h1y; ((f16x2*)(hb + (size_t)P1 * NS))[lane] = o;
    }
    if constexpr (TAU <= 2) {
        constexpr int P2 = PHYS[((TAU + 1) * (TAU + 2)) / 2 + 1];
        o[0] = (_Float16)h2x; o[1] = (_Float16)h2y; ((f16x2*)(hb + (size_t)P2 * NS))[lane] = o;
    }
    if constexpr (TAU <= 1) {
        constexpr int P3 = PHYS[((TAU + 2) * (TAU + 3)) / 2 + 2];
        o[0] = (_Float16)h3x; o[1] = (_Float16)h3y; ((f16x2*)(hb + (size_t)P3 * NS))[lane] = o;
    }
    if constexpr (TAU == 0) {
        constexpr int P4 = PHYS[9];
        o[0] = (_Float16)h4x; o[1] = (_Float16)h4y; ((f16x2*)(hb + (size_t)P4 * NS))[lane] = o;
    }
}

// -------- phase 2: C = sum_s A_s @ W_s, fused bias+relu+residual+L2norm --------
// W_s staged in LDS (XOR-swizzled store + swizzled read), A/next-W reg prefetch.

struct GemmArgs {
    const _Float16* Aslot[7];   // per-sublayer A base pointers
    const _Float16* Wt;         // 13 x [n][k] f16
    const _Float16* xin;        // xh[t], residual source
    const float* bias;          // bias_sums + t*128
    float* outf;                // fp32 out (final layer) or null
    _Float16* outh;             // xh[t+1] or null
    int N;
    int wsel[7];
};

template <int NSUB>
__global__ __launch_bounds__(128, 2) void k_gemm(GemmArgs a) {
    __shared__ __align__(16) _Float16 Wlds[DIM * DIM];   // 32 KB, swizzled
    const int tid = threadIdx.x, wv = tid >> 6, lane = tid & 63;
    const int rowBase = blockIdx.x * 64 + wv * 32;
    const int lr = lane & 15, lg = lane >> 4;

    int r0 = rowBase + lr, r1 = rowBase + 16 + lr;
    if (r0 >= a.N) r0 = a.N - 1;
    if (r1 >= a.N) r1 = a.N - 1;

    f32x4 acc[2][8];
    #pragma unroll
    for (int rt = 0; rt < 2; ++rt)
        #pragma unroll
        for (int ct = 0; ct < 8; ++ct)
            acc[rt][ct] = (f32x4){0.f, 0.f, 0.f, 0.f};

    const int sw = (lr & 7) << 4;   // read-side XOR

    {
        const _Float16* Ws = a.Wt + (size_t)a.wsel[0] * (DIM * DIM);
        f16x8 w[16];
        #pragma unroll
        for (int i = 0; i < 16; ++i)
            w[i] = *(const f16x8*)((const char*)Ws + i * 2048 + tid * 16);
        #pragma unroll
        for (int i = 0; i < 16; ++i) {
            const int p = i * 2048 + tid * 16;
            const int q = p ^ (((p >> 8) & 7) << 4);
            *(f16x8*)((char*)Wlds + q) = w[i];
        }
    }
    f16x8 afA[2][4], afB[2][4];
    #pragma unroll
    for (int ks = 0; ks < 4; ++ks) {
        afA[0][ks] = *(const f16x8*)(a.Aslot[0] + (size_t)r0 * DIM + ks * 32 + lg * 8);
        afB[0][ks] = *(const f16x8*)(a.Aslot[0] + (size_t)r1 * DIM + ks * 32 + lg * 8);
    }
    __syncthreads();

    #pragma unroll
    for (int s = 0; s < NSUB; ++s) {
        const int cur = s & 1, nxt = cur ^ 1;
        f16x8 w[16];
        if (s + 1 < NSUB) {
            const _Float16* Wn = a.Wt + (size_t)a.wsel[s + 1] * (DIM * DIM);
            #pragma unroll
            for (int i = 0; i < 16; ++i)
                w[i] = *(const f16x8*)((const char*)Wn + i * 2048 + tid * 16);
            const _Float16* An = a.Aslot[s + 1];
            #pragma unroll
            for (int ks = 0; ks < 4; ++ks) {
                afA[nxt][ks] = *(const f16x8*)(An + (size_t)r0 * DIM + ks * 32 + lg * 8);
                afB[nxt][ks] = *(const f16x8*)(An + (size_t)r1 * DIM + ks * 32 + lg * 8);
            }
        }
        #pragma unroll
        for (int ks = 0; ks < 4; ++ks) {
            const int cb = (ks * 32 + lg * 8) * 2;
            #pragma unroll
            for (int ct = 0; ct < 8; ++ct) {
                const int addr = (ct * 16 + lr) * 256 + (cb ^ sw);
                const f16x8 bf = *(const f16x8*)((const char*)Wlds + addr);
                acc[0][ct] = __builtin_amdgcn_mfma_f32_16x16x32_f16(afA[cur][ks], bf, acc[0][ct], 0, 0, 0);
                acc[1][ct] = __builtin_amdgcn_mfma_f32_16x16x32_f16(afB[cur][ks], bf, acc[1][ct], 0, 0, 0);
            }
        }
        __syncthreads();
        if (s + 1 < NSUB) {
            #pragma unroll
            for (int i = 0; i < 16; ++i) {
                const int p = i * 2048 + tid * 16;
                const int q = p ^ (((p >> 8) & 7) << 4);
                *(f16x8*)((char*)Wlds + q) = w[i];
            }
            __syncthreads();
        }
    }

    float bv[8];
    #pragma unroll
    for (int ct = 0; ct < 8; ++ct) bv[ct] = a.bias[ct * 16 + lr];

    #pragma unroll
    for (int rt = 0; rt < 2; ++rt) {
        #pragma unroll
        for (int rg = 0; rg < 4; ++rg) {
            const int row = rowBase + rt * 16 + lg * 4 + rg;
            const int rr = (row < a.N) ? row : a.N - 1;
            float v[8];
            float ss = 0.f;
            #pragma unroll
            for (int ct = 0; ct < 8; ++ct) {
                const float xval = (float)a.xin[(size_t)rr * DIM + ct * 16 + lr];
                const float tv = fmaxf(acc[rt][ct][rg] + bv[ct], 0.f) + xval;
                v[ct] = tv;
                ss += tv * tv;
            }
            ss += __shfl_xor(ss, 1, 64);
            ss += __shfl_xor(ss, 2, 64);
            ss += __shfl_xor(ss, 4, 64);
            ss += __shfl_xor(ss, 8, 64);
            const float inv = 1.f / fmaxf(sqrtf(ss), 1e-12f);
            if (row < a.N) {
                #pragma unroll
                for (int ct = 0; ct < 8; ++ct) {
                    const int col = ct * 16 + lr;
                    const float ov = v[ct] * inv;
                    if (a.outf) a.outf[(size_t)row * DIM + col] = ov;
                    if (a.outh) a.outh[(size_t)row * DIM + col] = (_Float16)ov;
                }
            }
        }
    }
}

// ---------------- launch ----------------

static inline size_t align_up(size_t v, size_t a) { return (v + a - 1) & ~(a - 1); }

extern "C" void kernel_launch(void* const* d_in, const int* in_sizes, int n_in,
                              void* d_out, int out_size, void* d_ws, size_t ws_size,
                              hipStream_t stream) {
    const float* x        = (const float*)d_in[0];
    const int* edge_index = (const int*)d_in[1];
    const int* edge_hop   = (const int*)d_in[2];
    const int* edge_type  = (const int*)d_in[3];
    const float* W_edge   = (const float*)d_in[4];
    const float* b_edge   = (const float*)d_in[5];
    const float* W_hop    = (const float*)d_in[6];
    const float* b_hop    = (const float*)d_in[7];
    float* out = (float*)d_out;

    int N = in_sizes[0] / DIM;   // 50000
    int E = in_sizes[2];         // 600000
    const int* srcA = edge_index;
    const int* dstA = edge_index + E;

    size_t NSh = (size_t)N * DIM * sizeof(_Float16);
    size_t off = 0;
    char* wsb = (char*)d_ws;
    _Float16* xh0     = (_Float16*)(wsb + off);  off = align_up(off + NSh, 64);
    _Float16* xh1     = (_Float16*)(wsb + off);  off = align_up(off + NSh, 64);
    _Float16* xh2     = (_Float16*)(wsb + off);  off = align_up(off + NSh, 64);
    _Float16* xh3     = (_Float16*)(wsb + off);  off = align_up(off + NSh, 64);
    _Float16* Atype   = (_Float16*)(wsb + off);  off = align_up(off + 3 * NSh, 64);
    _Float16* Ahop    = (_Float16*)(wsb + off);  off = align_up(off + 7 * NSh, 64);
    _Float16* Wt      = (_Float16*)(wsb + off);  off = align_up(off + 13 * DIM * DIM * sizeof(_Float16), 64);
    int* counts       = (int*)(wsb + off);       off = align_up(off + (size_t)N * 4, 64);
    int* partial      = (int*)(wsb + off);       off = align_up(off + (size_t)N * 4, 64);
    int* blockSums    = (int*)(wsb + off);       off = align_up(off + 64 * 4, 64);
    int* row_ptr      = (int*)(wsb + off);       off = align_up(off + (size_t)(N + 1) * 4, 64);
    int* cursor       = (int*)(wsb + off);       off = align_up(off + (size_t)(N + 1) * 4, 64);
    unsigned* csr     = (unsigned*)(wsb + off);  off = align_up(off + (size_t)E * 4, 64);
    float* bias_sums  = (float*)(wsb + off);     off = align_up(off + 4 * DIM * 4, 64);
    (void)ws_size;  // ~187 MB

    // CSR build
    hipMemsetAsync(counts, 0, (size_t)N * 4, stream);
    k_count<<<(E + 255) / 256, 256, 0, stream>>>(dstA, E, counts);
    int nb = (N + 1023) / 1024;   // 49
    k_scan1<<<nb, 1024, 0, stream>>>(counts, N, partial, blockSums);
    k_scan2<<<1, 64, 0, stream>>>(blockSums, nb);
    k_scan3<<<nb, 1024, 0, stream>>>(partial, blockSums, N, row_ptr, cursor);
    k_scatter<<<(E + 255) / 256, 256, 0, stream>>>(srcA, dstA, edge_type, edge_hop, E, cursor, csr);
    k_bias<<<4, DIM, 0, stream>>>(b_edge, b_hop, bias_sums);

    // f16 conversions
    k_convX<<<(N * DIM / 8 + 255) / 256, 256, 0, stream>>>(x, xh0, N * DIM);
    k_convW<<<13, 256, 0, stream>>>(W_edge, W_hop, Wt);

    _Float16* xh_ptr[4] = { xh0, xh1, xh2, xh3 };
    const size_t NS = (size_t)N * DIM;

    for (int t = 0; t < NLAYER; ++t) {
        GatherArgs g;
        g.xt = xh_ptr[t];
        g.Atype = Atype; g.Ahop = Ahop;
        g.row_ptr = row_ptr; g.csr = csr; g.N = N;
        switch (t) {
            case 0: k_gather<0><<<N, 64, 0, stream>>>(g); break;
            case 1: k_gather<1><<<N, 64, 0, stream>>>(g); break;
            case 2: k_gather<2><<<N, 64, 0, stream>>>(g); break;
            default: k_gather<3><<<N, 64, 0, stream>>>(g); break;
        }

        GemmArgs m;
        m.Wt = Wt; m.xin = xh_ptr[t];
        m.bias = bias_sums + t * DIM;
        m.outf = (t == 3) ? out : nullptr;
        m.outh = (t < 3) ? xh_ptr[t + 1] : nullptr;
        m.N = N;
        const int nsub = t + 4;
        const int base = t * (t + 1) / 2;
        for (int s = 0; s < 3; ++s) { m.wsel[s] = s; m.Aslot[s] = Atype + (size_t)s * NS; }
        for (int j = 0; j <= t; ++j) {
            m.wsel[3 + j] = 3 + base + j;
            m.Aslot[3 + j] = Ahop + (size_t)PHYS[base + j] * NS;
        }
        for (int s = nsub; s < 7; ++s) { m.wsel[s] = 0; m.Aslot[s] = Atype; }

        const int gb = (N + 63) / 64;
        switch (nsub) {
            case 4: k_gemm<4><<<gb, 128, 0, stream>>>(m); break;
            case 5: k_gemm<5><<<gb, 128, 0, stream>>>(m); break;
            case 6: k_gemm<6><<<gb, 128, 0, stream>>>(m); break;
            default: k_gemm<7><<<gb, 128, 0, stream>>>(m); break;
        }
    }
}

// Round 11
// 298.735 us; speedup vs baseline: 2.2430x; 1.1503x over previous
//
#include <hip/hip_runtime.h>
#include <hip/hip_bf16.h>

#define DIM 128
#define NLAYER 4
#define CHUNK 4096     // edges per block in CSR-build pass 1

typedef _Float16 f16x8 __attribute__((ext_vector_type(8)));
typedef _Float16 f16x2 __attribute__((ext_vector_type(2)));
typedef float f32x4 __attribute__((ext_vector_type(4)));

// Physical slot map for the 10 logical hop slots (ring allocation, peak live = 6).
// idx(t',k) = t'(t'+1)/2 + (k-1). Collision-checked: lifetimes disjoint per phys slot.
static constexpr int PHYS[10] = {0, 4, 1, 0, 5, 2, 1, 4, 6, 3};

// ============ CSR build: bucketed two-pass, coalesced final writes ============
// bucket = dst >> 8 (196 buckets). Pass1: per-block LDS hist + LDS-cursor scatter
// of (dst<<32|word) into bucket-segmented ebuf. Pass2: one block per bucket sorts
// locally by dst, writes csr coalesced and row_ptr directly.
// word = src<<8 | typ<<24 | hop<<26 (src pre-scaled to byte offset).

__global__ __launch_bounds__(256) void k_hist1(const int* __restrict__ dst, int E,
                                               int B1, int NBKT, int* __restrict__ ghist) {
    __shared__ int h[256];
    h[threadIdx.x] = 0;
    __syncthreads();
    const int base = blockIdx.x * CHUNK;
    #pragma unroll
    for (int i = 0; i < CHUNK / 256; ++i) {
        int e = base + i * 256 + threadIdx.x;
        if (e < E) atomicAdd(&h[dst[e] >> 8], 1);
    }
    __syncthreads();
    if (threadIdx.x < NBKT) ghist[threadIdx.x * B1 + blockIdx.x] = h[threadIdx.x];
}

__global__ __launch_bounds__(1024) void k_scan1(const int* __restrict__ in, int n,
                                                int* __restrict__ partial,
                                                int* __restrict__ blockSums) {
    __shared__ int sd[1024];
    int tid = threadIdx.x;
    int i = blockIdx.x * 1024 + tid;
    int v = (i < n) ? in[i] : 0;
    sd[tid] = v;
    __syncthreads();
    for (int off = 1; off < 1024; off <<= 1) {
        int t = (tid >= off) ? sd[tid - off] : 0;
        __syncthreads();
        sd[tid] += t;
        __syncthreads();
    }
    if (i < n) partial[i] = sd[tid];
    if (tid == 1023) blockSums[blockIdx.x] = sd[1023];
}

__global__ void k_scan2(int* __restrict__ bs, int nb) {   // nb <= 64
    int lane = threadIdx.x;
    int v = (lane < nb) ? bs[lane] : 0;
    for (int off = 1; off < 64; off <<= 1) {
        int t = __shfl_up(v, off, 64);
        if (lane >= off) v += t;
    }
    int ex = __shfl_up(v, 1, 64);
    if (lane == 0) ex = 0;
    if (lane < nb) bs[lane] = ex;
}

__global__ __launch_bounds__(1024) void k_scan3b(const int* __restrict__ partial,
                                                 const int* __restrict__ bs, int n,
                                                 int* __restrict__ outEx) {
    int i = blockIdx.x * blockDim.x + threadIdx.x;
    if (i < n) outEx[i + 1] = partial[i] + bs[i >> 10];
    if (i == 0) outEx[0] = 0;
}

__global__ __launch_bounds__(256) void k_scat1(const int* __restrict__ srcA,
                                               const int* __restrict__ dstA,
                                               const int* __restrict__ typA,
                                               const int* __restrict__ hopA,
                                               int E, int B1, int NBKT,
                                               const int* __restrict__ gcur,
                                               unsigned long long* __restrict__ ebuf) {
    __shared__ int cur[256];
    if (threadIdx.x < NBKT) cur[threadIdx.x] = gcur[threadIdx.x * B1 + blockIdx.x];
    __syncthreads();
    const int base = blockIdx.x * CHUNK;
    #pragma unroll
    for (int i = 0; i < CHUNK / 256; ++i) {
        int e = base + i * 256 + threadIdx.x;
        if (e < E) {
            int d = dstA[e];
            unsigned w = ((unsigned)srcA[e] << 8) | ((unsigned)typA[e] << 24)
                       | ((unsigned)hopA[e] << 26);
            int p = atomicAdd(&cur[d >> 8], 1);
            ebuf[p] = ((unsigned long long)(unsigned)d << 32) | w;
        }
    }
}

__global__ __launch_bounds__(256) void k_finalize(const unsigned long long* __restrict__ ebuf,
                                                  const int* __restrict__ gcur,
                                                  int E, int B1, int NBKT, int N,
                                                  unsigned* __restrict__ csr,
                                                  int* __restrict__ row_ptr) {
    __shared__ int cnt[256], sd[256], off2[256];
    __shared__ unsigned stg[8192];   // >= max bucket size (~3100 expected)
    const int bkt = blockIdx.x, tid = threadIdx.x;
    const int base = gcur[bkt * B1];
    const int endv = (bkt + 1 < NBKT) ? gcur[(bkt + 1) * B1] : E;
    const int n = endv - base;

    cnt[tid] = 0;
    __syncthreads();
    for (int i = tid; i < n; i += 256)
        atomicAdd(&cnt[(int)((ebuf[base + i] >> 32) & 255)], 1);
    __syncthreads();

    sd[tid] = cnt[tid];
    __syncthreads();
    for (int o = 1; o < 256; o <<= 1) {
        int t = (tid >= o) ? sd[tid - o] : 0;
        __syncthreads();
        sd[tid] += t;
        __syncthreads();
    }
    const int ex = (tid > 0) ? sd[tid - 1] : 0;
    off2[tid] = ex;
    const int node = bkt * 256 + tid;
    if (node < N) row_ptr[node] = base + ex;
    if (bkt == NBKT - 1 && tid == 0) row_ptr[N] = E;
    __syncthreads();

    for (int i = tid; i < n; i += 256) {
        const unsigned long long ld = ebuf[base + i];
        const int r = atomicAdd(&off2[(int)((ld >> 32) & 255)], 1);
        stg[r] = (unsigned)ld;
    }
    __syncthreads();
    for (int i = tid; i < n; i += 256) csr[base + i] = stg[i];
}

__global__ void k_bias(const float* __restrict__ b_edge, const float* __restrict__ b_hop,
                       float* __restrict__ bias_sums) {
    int t = blockIdx.x, d = threadIdx.x;
    float s = b_edge[d] + b_edge[DIM + d] + b_edge[2 * DIM + d];
    int base = t * (t + 1) / 2;
    for (int k = 1; k <= t + 1; ++k) s += b_hop[(base + k - 1) * DIM + d];
    bias_sums[t * DIM + d] = s;
}

// ---------------- f16 conversions ----------------

__global__ void k_convX(const float* __restrict__ in, _Float16* __restrict__ out, int n) {
    int i = (blockIdx.x * blockDim.x + threadIdx.x) * 8;
    if (i >= n) return;
    float4 a = ((const float4*)(in + i))[0];
    float4 b = ((const float4*)(in + i))[1];
    f16x8 o;
    o[0] = (_Float16)a.x; o[1] = (_Float16)a.y; o[2] = (_Float16)a.z; o[3] = (_Float16)a.w;
    o[4] = (_Float16)b.x; o[5] = (_Float16)b.y; o[6] = (_Float16)b.z; o[7] = (_Float16)b.w;
    *(f16x8*)(out + i) = o;
}

// 13 weight matrices, fp32 row-major [k][n] -> f16 transposed [n][k]
__global__ __launch_bounds__(256) void k_convW(const float* __restrict__ W_edge,
                                               const float* __restrict__ W_hop,
                                               _Float16* __restrict__ Wt) {
    int s = blockIdx.x;
    const float* src = (s < 3) ? (W_edge + (size_t)s * DIM * DIM)
                               : (W_hop + (size_t)(s - 3) * DIM * DIM);
    _Float16* dstp = Wt + (size_t)s * DIM * DIM;
    for (int it = 0; it < 64; ++it) {
        int e = it * 256 + threadIdx.x;
        int n = e >> 7, k = e & 127;
        dstp[e] = (_Float16)src[k * DIM + n];
    }
}

// -------- phase 1: single-pass gather; future hop slots accumulated now --------

struct GatherArgs {
    const _Float16* __restrict__ xt;    // xh[TAU]
    _Float16* __restrict__ Atype;       // [3][N][128]
    _Float16* __restrict__ Ahop;        // [7][N][128] physical ring slots
    const int* __restrict__ row_ptr;
    const unsigned* __restrict__ csr;
    int N;
};

template <int TAU>
__global__ __launch_bounds__(64) void k_gather(GatherArgs a) {
    const int node = blockIdx.x;            // wave-uniform
    const int lane = threadIdx.x;
    const size_t NS = (size_t)a.N * DIM;

    const char* xtl = (const char*)a.xt + lane * 4;

    float t0x = 0, t0y = 0, t1x = 0, t1y = 0, t2x = 0, t2y = 0;
    float h1x = 0, h1y = 0, h2x = 0, h2y = 0, h3x = 0, h3y = 0, h4x = 0, h4y = 0;

    const int e0 = a.row_ptr[node], e1 = a.row_ptr[node + 1];
    int e = e0;

    #define ACCUM(m, v)                                                        \
        {                                                                      \
            const int typ = (int)((m) >> 24) & 3;                              \
            const int hop = (int)((m) >> 26);                                  \
            const float vx = (float)(v)[0], vy = (float)(v)[1];                \
            if (typ == 0)      { t0x += vx; t0y += vy; }                       \
            else if (typ == 1) { t1x += vx; t1y += vy; }                       \
            else               { t2x += vx; t2y += vy; }                       \
            if (hop == 1)                    { h1x += vx; h1y += vy; }         \
            else if (TAU <= 2 && hop == 2)   { h2x += vx; h2y += vy; }         \
            else if (TAU <= 1 && hop == 3)   { h3x += vx; h3y += vy; }         \
            else if (TAU == 0 && hop == 4)   { h4x += vx; h4y += vy; }         \
        }

    for (; e + 8 <= e1; e += 8) {
        unsigned mm[8];
        #pragma unroll
        for (int j = 0; j < 8; ++j) mm[j] = a.csr[e + j];
        f16x2 vv[8];
        #pragma unroll
        for (int j = 0; j < 8; ++j)
            vv[j] = *(const f16x2*)(xtl + (mm[j] & 0xFFFFFF));
        #pragma unroll
        for (int j = 0; j < 8; ++j) ACCUM(mm[j], vv[j])
    }
    for (; e + 4 <= e1; e += 4) {
        unsigned mm[4];
        #pragma unroll
        for (int j = 0; j < 4; ++j) mm[j] = a.csr[e + j];
        f16x2 vv[4];
        #pragma unroll
        for (int j = 0; j < 4; ++j)
            vv[j] = *(const f16x2*)(xtl + (mm[j] & 0xFFFFFF));
        #pragma unroll
        for (int j = 0; j < 4; ++j) ACCUM(mm[j], vv[j])
    }
    for (; e < e1; ++e) {
        const unsigned m = a.csr[e];
        const f16x2 v = *(const f16x2*)(xtl + (m & 0xFFFFFF));
        ACCUM(m, v)
    }
    #undef ACCUM

    _Float16* tb = a.Atype + (size_t)node * DIM;
    f16x2 o;
    o[0] = (_Float16)t0x; o[1] = (_Float16)t0y; ((f16x2*)(tb + 0 * NS))[lane] = o;
    o[0] = (_Float16)t1x; o[1] = (_Float16)t1y; ((f16x2*)(tb + 1 * NS))[lane] = o;
    o[0] = (_Float16)t2x; o[1] = (_Float16)t2y; ((f16x2*)(tb + 2 * NS))[lane] = o;

    _Float16* hb = a.Ahop + (size_t)node * DIM;
    {
        constexpr int P1 = PHYS[(TAU * (TAU + 1)) / 2];
        o[0] = (_Float16)h1x; o[1] = (_Float16)h1y; ((f16x2*)(hb + (size_t)P1 * NS))[lane] = o;
    }
    if constexpr (TAU <= 2) {
        constexpr int P2 = PHYS[((TAU + 1) * (TAU + 2)) / 2 + 1];
        o[0] = (_Float16)h2x; o[1] = (_Float16)h2y; ((f16x2*)(hb + (size_t)P2 * NS))[lane] = o;
    }
    if constexpr (TAU <= 1) {
        constexpr int P3 = PHYS[((TAU + 2) * (TAU + 3)) / 2 + 2];
        o[0] = (_Float16)h3x; o[1] = (_Float16)h3y; ((f16x2*)(hb + (size_t)P3 * NS))[lane] = o;
    }
    if constexpr (TAU == 0) {
        constexpr int P4 = PHYS[9];
        o[0] = (_Float16)h4x; o[1] = (_Float16)h4y; ((f16x2*)(hb + (size_t)P4 * NS))[lane] = o;
    }
}

// -------- phase 2: C = sum_s A_s @ W_s, fused bias+relu+residual+L2norm --------

struct GemmArgs {
    const _Float16* Aslot[7];
    const _Float16* Wt;
    const _Float16* xin;
    const float* bias;
    float* outf;
    _Float16* outh;
    int N;
    int wsel[7];
};

template <int NSUB>
__global__ __launch_bounds__(128, 2) void k_gemm(GemmArgs a) {
    __shared__ __align__(16) _Float16 Wlds[DIM * DIM];   // 32 KB, swizzled
    const int tid = threadIdx.x, wv = tid >> 6, lane = tid & 63;
    const int rowBase = blockIdx.x * 64 + wv * 32;
    const int lr = lane & 15, lg = lane >> 4;

    int r0 = rowBase + lr, r1 = rowBase + 16 + lr;
    if (r0 >= a.N) r0 = a.N - 1;
    if (r1 >= a.N) r1 = a.N - 1;

    f32x4 acc[2][8];
    #pragma unroll
    for (int rt = 0; rt < 2; ++rt)
        #pragma unroll
        for (int ct = 0; ct < 8; ++ct)
            acc[rt][ct] = (f32x4){0.f, 0.f, 0.f, 0.f};

    const int sw = (lr & 7) << 4;

    {
        const _Float16* Ws = a.Wt + (size_t)a.wsel[0] * (DIM * DIM);
        f16x8 w[16];
        #pragma unroll
        for (int i = 0; i < 16; ++i)
            w[i] = *(const f16x8*)((const char*)Ws + i * 2048 + tid * 16);
        #pragma unroll
        for (int i = 0; i < 16; ++i) {
            const int p = i * 2048 + tid * 16;
            const int q = p ^ (((p >> 8) & 7) << 4);
            *(f16x8*)((char*)Wlds + q) = w[i];
        }
    }
    f16x8 afA[2][4], afB[2][4];
    #pragma unroll
    for (int ks = 0; ks < 4; ++ks) {
        afA[0][ks] = *(const f16x8*)(a.Aslot[0] + (size_t)r0 * DIM + ks * 32 + lg * 8);
        afB[0][ks] = *(const f16x8*)(a.Aslot[0] + (size_t)r1 * DIM + ks * 32 + lg * 8);
    }
    __syncthreads();

    #pragma unroll
    for (int s = 0; s < NSUB; ++s) {
        const int cur = s & 1, nxt = cur ^ 1;
        f16x8 w[16];
        if (s + 1 < NSUB) {
            const _Float16* Wn = a.Wt + (size_t)a.wsel[s + 1] * (DIM * DIM);
            #pragma unroll
            for (int i = 0; i < 16; ++i)
                w[i] = *(const f16x8*)((const char*)Wn + i * 2048 + tid * 16);
            const _Float16* An = a.Aslot[s + 1];
            #pragma unroll
            for (int ks = 0; ks < 4; ++ks) {
                afA[nxt][ks] = *(const f16x8*)(An + (size_t)r0 * DIM + ks * 32 + lg * 8);
                afB[nxt][ks] = *(const f16x8*)(An + (size_t)r1 * DIM + ks * 32 + lg * 8);
            }
        }
        #pragma unroll
        for (int ks = 0; ks < 4; ++ks) {
            const int cb = (ks * 32 + lg * 8) * 2;
            #pragma unroll
            for (int ct = 0; ct < 8; ++ct) {
                const int addr = (ct * 16 + lr) * 256 + (cb ^ sw);
                const f16x8 bf = *(const f16x8*)((const char*)Wlds + addr);
                acc[0][ct] = __builtin_amdgcn_mfma_f32_16x16x32_f16(afA[cur][ks], bf, acc[0][ct], 0, 0, 0);
                acc[1][ct] = __builtin_amdgcn_mfma_f32_16x16x32_f16(afB[cur][ks], bf, acc[1][ct], 0, 0, 0);
            }
        }
        __syncthreads();
        if (s + 1 < NSUB) {
            #pragma unroll
            for (int i = 0; i < 16; ++i) {
                const int p = i * 2048 + tid * 16;
                const int q = p ^ (((p >> 8) & 7) << 4);
                *(f16x8*)((char*)Wlds + q) = w[i];
            }
            __syncthreads();
        }
    }

    float bv[8];
    #pragma unroll
    for (int ct = 0; ct < 8; ++ct) bv[ct] = a.bias[ct * 16 + lr];

    #pragma unroll
    for (int rt = 0; rt < 2; ++rt) {
        #pragma unroll
        for (int rg = 0; rg < 4; ++rg) {
            const int row = rowBase + rt * 16 + lg * 4 + rg;
            const int rr = (row < a.N) ? row : a.N - 1;
            float v[8];
            float ss = 0.f;
            #pragma unroll
            for (int ct = 0; ct < 8; ++ct) {
                const float xval = (float)a.xin[(size_t)rr * DIM + ct * 16 + lr];
                const float tv = fmaxf(acc[rt][ct][rg] + bv[ct], 0.f) + xval;
                v[ct] = tv;
                ss += tv * tv;
            }
            ss += __shfl_xor(ss, 1, 64);
            ss += __shfl_xor(ss, 2, 64);
            ss += __shfl_xor(ss, 4, 64);
            ss += __shfl_xor(ss, 8, 64);
            const float inv = 1.f / fmaxf(sqrtf(ss), 1e-12f);
            if (row < a.N) {
                #pragma unroll
                for (int ct = 0; ct < 8; ++ct) {
                    const int col = ct * 16 + lr;
                    const float ov = v[ct] * inv;
                    if (a.outf) a.outf[(size_t)row * DIM + col] = ov;
                    if (a.outh) a.outh[(size_t)row * DIM + col] = (_Float16)ov;
                }
            }
        }
    }
}

// ---------------- launch ----------------

static inline size_t align_up(size_t v, size_t a) { return (v + a - 1) & ~(a - 1); }

extern "C" void kernel_launch(void* const* d_in, const int* in_sizes, int n_in,
                              void* d_out, int out_size, void* d_ws, size_t ws_size,
                              hipStream_t stream) {
    const float* x        = (const float*)d_in[0];
    const int* edge_index = (const int*)d_in[1];
    const int* edge_hop   = (const int*)d_in[2];
    const int* edge_type  = (const int*)d_in[3];
    const float* W_edge   = (const float*)d_in[4];
    const float* b_edge   = (const float*)d_in[5];
    const float* W_hop    = (const float*)d_in[6];
    const float* b_hop    = (const float*)d_in[7];
    float* out = (float*)d_out;

    int N = in_sizes[0] / DIM;   // 50000
    int E = in_sizes[2];         // 600000
    const int* srcA = edge_index;
    const int* dstA = edge_index + E;

    const int B1 = (E + CHUNK - 1) / CHUNK;     // 147
    const int NBKT = (N + 255) >> 8;            // 196
    const int n2 = NBKT * B1;                   // 28812

    size_t NSh = (size_t)N * DIM * sizeof(_Float16);
    size_t off = 0;
    char* wsb = (char*)d_ws;
    _Float16* xh0     = (_Float16*)(wsb + off);  off = align_up(off + NSh, 64);
    _Float16* xh1     = (_Float16*)(wsb + off);  off = align_up(off + NSh, 64);
    _Float16* xh2     = (_Float16*)(wsb + off);  off = align_up(off + NSh, 64);
    _Float16* xh3     = (_Float16*)(wsb + off);  off = align_up(off + NSh, 64);
    _Float16* Atype   = (_Float16*)(wsb + off);  off = align_up(off + 3 * NSh, 64);
    _Float16* Ahop    = (_Float16*)(wsb + off);  off = align_up(off + 7 * NSh, 64);
    _Float16* Wt      = (_Float16*)(wsb + off);  off = align_up(off + 13 * DIM * DIM * sizeof(_Float16), 64);
    int* ghist        = (int*)(wsb + off);       off = align_up(off + (size_t)n2 * 4, 64);
    int* partial      = (int*)(wsb + off);       off = align_up(off + (size_t)n2 * 4, 64);
    int* blockSums    = (int*)(wsb + off);       off = align_up(off + 64 * 4, 64);
    int* gcur         = (int*)(wsb + off);       off = align_up(off + (size_t)(n2 + 1) * 4, 64);
    int* row_ptr      = (int*)(wsb + off);       off = align_up(off + (size_t)(N + 1) * 4, 64);
    unsigned long long* ebuf = (unsigned long long*)(wsb + off);
                                                 off = align_up(off + (size_t)E * 8, 64);
    unsigned* csr     = (unsigned*)(wsb + off);  off = align_up(off + (size_t)E * 4, 64);
    float* bias_sums  = (float*)(wsb + off);     off = align_up(off + 4 * DIM * 4, 64);
    (void)ws_size;  // ~195 MB

    // CSR build (bucketed two-pass)
    k_hist1<<<B1, 256, 0, stream>>>(dstA, E, B1, NBKT, ghist);
    int nb2 = (n2 + 1023) / 1024;   // 29
    k_scan1<<<nb2, 1024, 0, stream>>>(ghist, n2, partial, blockSums);
    k_scan2<<<1, 64, 0, stream>>>(blockSums, nb2);
    k_scan3b<<<nb2, 1024, 0, stream>>>(partial, blockSums, n2, gcur);
    k_scat1<<<B1, 256, 0, stream>>>(srcA, dstA, edge_type, edge_hop, E, B1, NBKT, gcur, ebuf);
    k_finalize<<<NBKT, 256, 0, stream>>>(ebuf, gcur, E, B1, NBKT, N, csr, row_ptr);
    k_bias<<<4, DIM, 0, stream>>>(b_edge, b_hop, bias_sums);

    // f16 conversions
    k_convX<<<(N * DIM / 8 + 255) / 256, 256, 0, stream>>>(x, xh0, N * DIM);
    k_convW<<<13, 256, 0, stream>>>(W_edge, W_hop, Wt);

    _Float16* xh_ptr[4] = { xh0, xh1, xh2, xh3 };
    const size_t NS = (size_t)N * DIM;

    for (int t = 0; t < NLAYER; ++t) {
        GatherArgs g;
        g.xt = xh_ptr[t];
        g.Atype = Atype; g.Ahop = Ahop;
        g.row_ptr = row_ptr; g.csr = csr; g.N = N;
        switch (t) {
            case 0: k_gather<0><<<N, 64, 0, stream>>>(g); break;
            case 1: k_gather<1><<<N, 64, 0, stream>>>(g); break;
            case 2: k_gather<2><<<N, 64, 0, stream>>>(g); break;
            default: k_gather<3><<<N, 64, 0, stream>>>(g); break;
        }

        GemmArgs m;
        m.Wt = Wt; m.xin = xh_ptr[t];
        m.bias = bias_sums + t * DIM;
        m.outf = (t == 3) ? out : nullptr;
        m.outh = (t < 3) ? xh_ptr[t + 1] : nullptr;
        m.N = N;
        const int nsub = t + 4;
        const int base = t * (t + 1) / 2;
        for (int s = 0; s < 3; ++s) { m.wsel[s] = s; m.Aslot[s] = Atype + (size_t)s * NS; }
        for (int j = 0; j <= t; ++j) {
            m.wsel[3 + j] = 3 + base + j;
            m.Aslot[3 + j] = Ahop + (size_t)PHYS[base + j] * NS;
        }
        for (int s = nsub; s < 7; ++s) { m.wsel[s] = 0; m.Aslot[s] = Atype; }

        const int gb = (N + 63) / 64;
        switch (nsub) {
            case 4: k_gemm<4><<<gb, 128, 0, stream>>>(m); break;
            case 5: k_gemm<5><<<gb, 128, 0, stream>>>(m); break;
            case 6: k_gemm<6><<<gb, 128, 0, stream>>>(m); break;
            default: k_gemm<7><<<gb, 128, 0, stream>>>(m); break;
        }
    }
}